// Round 3
// baseline (598.120 us; speedup 1.0000x reference)
//
#include <hip/hip_runtime.h>
#include <hip/hip_bf16.h>

#define N_NODES 50000
#define N_EDGES 800000

typedef __attribute__((ext_vector_type(8))) short bf16x8;
typedef __attribute__((ext_vector_type(4))) float f32x4;

__device__ __forceinline__ float bf2f(unsigned short u) {
    unsigned int x = ((unsigned int)u) << 16;
    return __uint_as_float(x);
}
__device__ __forceinline__ unsigned short f2bf(float f) {
    unsigned int x = __float_as_uint(f);
    unsigned int lsb = (x >> 16) & 1u;
    x += 0x7fffu + lsb;
    return (unsigned short)(x >> 16);
}

// ---------------- CSR build ----------------

__global__ void k_zero(int* p, int n) {
    int i = blockIdx.x * blockDim.x + threadIdx.x;
    if (i < n) p[i] = 0;
}

__global__ void k_deg(const int* __restrict__ dst, int* __restrict__ deg) {
    int e = blockIdx.x * blockDim.x + threadIdx.x;
    if (e < N_EDGES) atomicAdd(&deg[dst[e]], 1);
}

// single-block chunk-serial exclusive scan: each thread serially owns a
// contiguous chunk; ONE 10-step ladder over 1024 partials (10 barriers total,
// vs ~1500 in the Hillis-Steele-per-chunk version that cost 94 us).
__global__ __launch_bounds__(1024) void k_scan(const int* __restrict__ deg,
                                               int* __restrict__ offsets,
                                               int* __restrict__ pos,
                                               float* __restrict__ inv_deg) {
    constexpr int T = 1024;
    constexpr int C = (N_NODES + T - 1) / T;  // 49
    __shared__ int partial[T];
    int tid = threadIdx.x;
    int start = tid * C;
    int end_ = min(start + C, N_NODES);
    int s = 0;
    for (int i = start; i < end_; ++i) s += deg[i];
    partial[tid] = s;
    __syncthreads();
    for (int off = 1; off < T; off <<= 1) {
        int t = (tid >= off) ? partial[tid - off] : 0;
        __syncthreads();
        partial[tid] += t;
        __syncthreads();
    }
    int excl = partial[tid] - s;  // exclusive prefix of this chunk
    for (int i = start; i < end_; ++i) {
        int d = deg[i];
        offsets[i] = excl;
        pos[i] = excl;
        inv_deg[i] = 1.0f / (float)max(d, 1);
        excl += d;
    }
    if (tid == T - 1) offsets[N_NODES] = partial[T - 1];
}

__global__ void k_scatter(const int* __restrict__ src, const int* __restrict__ dst,
                          int* __restrict__ pos, int* __restrict__ edge_src) {
    int e = blockIdx.x * blockDim.x + threadIdx.x;
    if (e < N_EDGES) {
        int p = atomicAdd(&pos[dst[e]], 1);
        edge_src[p] = src[e];
    }
}

// ---------------- fp32 -> bf16 bulk convert (features, done once) ----------------
__global__ void k_f2bf(const float2* __restrict__ in, unsigned int* __restrict__ outp, int n2) {
    int i = blockIdx.x * blockDim.x + threadIdx.x;
    if (i < n2) {
        float2 v = in[i];
        outp[i] = ((unsigned int)f2bf(v.y) << 16) | (unsigned int)f2bf(v.x);
    }
}

// ---------------- mean aggregation (one wave per node) ----------------
// h: [N,128] bf16; lane i reads one packed uint (256B/row/wave). fp32 accumulation.
__global__ void k_agg(const __hip_bfloat16* __restrict__ hv, const int* __restrict__ offsets,
                      const int* __restrict__ edge_src, const float* __restrict__ inv_deg,
                      __hip_bfloat16* __restrict__ msg) {
    int gid = blockIdx.x * blockDim.x + threadIdx.x;
    int node = gid >> 6;
    int lane = gid & 63;
    if (node >= N_NODES) return;
    int beg = offsets[node], end = offsets[node + 1];
    float a0 = 0.f, a1 = 0.f;
    const unsigned int* hp = (const unsigned int*)hv;  // 64 uints per row
    for (int i = beg; i < end; ++i) {
        int s = edge_src[i];
        unsigned int u = hp[(size_t)s * 64 + lane];
        a0 += bf2f((unsigned short)(u & 0xffffu));
        a1 += bf2f((unsigned short)(u >> 16));
    }
    float w = inv_deg[node];
    unsigned int packed = ((unsigned int)f2bf(a1 * w) << 16) | (unsigned int)f2bf(a0 * w);
    ((unsigned int*)msg)[(size_t)node * 64 + lane] = packed;
}

// ---------------- W fragment packing (fp32 weights -> bf16 B-fragments) ----------------
// Bcat[k][n], k in [0,256): k<128 -> Wself[k][n], else Wneigh[k-128][n]. W row-major [128][Dout].
// frag: lane of (ct,kt) holds B[kt*32 + (lane>>4)*8 + j][ct*16 + (lane&15)], j=0..7.
__global__ void k_wprep(const float* __restrict__ Wself, const float* __restrict__ Wneigh,
                        int Dout, __hip_bfloat16* __restrict__ frag) {
    int t = blockIdx.x * blockDim.x + threadIdx.x;
    int nCt = Dout >> 4;
    int total = nCt * 8 * 64;
    if (t >= total) return;
    int lane = t & 63;
    int kt = (t >> 6) & 7;
    int ct = t >> 9;
    int q = lane >> 4;
    int n = ct * 16 + (lane & 15);
    unsigned short* dstp = (unsigned short*)frag + ((size_t)((ct * 8 + kt) * 64 + lane)) * 8;
    #pragma unroll
    for (int j = 0; j < 8; ++j) {
        int k = kt * 32 + q * 8 + j;
        float v = (k < 128) ? Wself[k * Dout + n] : Wneigh[(k - 128) * Dout + n];
        dstp[j] = f2bf(v);
    }
}

// ---------------- fused GEMM + bias (+ relu + l2norm) ----------------
// out[n][:] = epilogue( Aself[n]@Wself + Aneigh[n]@Wneigh + b ), K=256 fused via MFMA.
// Block = 256 threads = 4 waves; wave handles 16 rows x Dout cols.
// LAST: no relu/l2norm, output fp32; else output bf16.
template <int NCT, bool LAST>
__global__ __launch_bounds__(256) void k_gemm(const __hip_bfloat16* __restrict__ Aself,
                                              const __hip_bfloat16* __restrict__ Aneigh,
                                              const __hip_bfloat16* __restrict__ frag,
                                              const float* __restrict__ bias,
                                              void* __restrict__ out_) {
    constexpr int Dout = NCT * 16;
    int tid = threadIdx.x;
    int wv = tid >> 6, lane = tid & 63;
    int n0 = blockIdx.x * 64 + wv * 16;
    if (n0 >= N_NODES) return;  // wave-uniform early exit, no LDS used
    int q = lane >> 4, l15 = lane & 15;
    int rowA = n0 + l15;
    if (rowA > N_NODES - 1) rowA = N_NODES - 1;  // clamp loads; stores guarded below

    f32x4 acc[NCT];
    #pragma unroll
    for (int c = 0; c < NCT; ++c) acc[c] = (f32x4){0.f, 0.f, 0.f, 0.f};

    const bf16x8* fragv = (const bf16x8*)frag;
    #pragma unroll
    for (int kt = 0; kt < 8; ++kt) {
        int kb = (kt & 3) * 32 + q * 8;
        const __hip_bfloat16* Ab = (kt < 4) ? Aself : Aneigh;
        bf16x8 a = *(const bf16x8*)(Ab + (size_t)rowA * 128 + kb);
        #pragma unroll
        for (int ct = 0; ct < NCT; ++ct) {
            bf16x8 b = fragv[(ct * 8 + kt) * 64 + lane];
            acc[ct] = __builtin_amdgcn_mfma_f32_16x16x32_bf16(a, b, acc[ct], 0, 0, 0);
        }
    }

    float ss[4] = {0.f, 0.f, 0.f, 0.f};
    #pragma unroll
    for (int ct = 0; ct < NCT; ++ct) {
        float bc = bias[ct * 16 + l15];
        #pragma unroll
        for (int r = 0; r < 4; ++r) {
            float v = acc[ct][r] + bc;
            if (!LAST) v = fmaxf(v, 0.0f);
            acc[ct][r] = v;
            ss[r] += v * v;
        }
    }

    float scale[4];
    #pragma unroll
    for (int r = 0; r < 4; ++r) {
        if (!LAST) {
            float s = ss[r];
            s += __shfl_xor(s, 1);
            s += __shfl_xor(s, 2);
            s += __shfl_xor(s, 4);
            s += __shfl_xor(s, 8);
            scale[r] = 1.0f / fmaxf(sqrtf(s), 1e-12f);
        } else {
            scale[r] = 1.0f;
        }
    }

    #pragma unroll
    for (int ct = 0; ct < NCT; ++ct) {
        #pragma unroll
        for (int r = 0; r < 4; ++r) {
            int row = n0 + q * 4 + r;
            if (row < N_NODES) {
                float v = acc[ct][r] * scale[r];
                if (LAST)
                    ((float*)out_)[(size_t)row * Dout + ct * 16 + l15] = v;
                else
                    ((unsigned short*)out_)[(size_t)row * Dout + ct * 16 + l15] = f2bf(v);
            }
        }
    }
}

// ---------------- host launch ----------------

extern "C" void kernel_launch(void* const* d_in, const int* in_sizes, int n_in,
                              void* d_out, int out_size, void* d_ws, size_t ws_size,
                              hipStream_t stream) {
    const float* features = (const float*)d_in[0];
    const int* src = (const int*)d_in[1];
    const int* dst = (const int*)d_in[2];
    const float* Ws0 = (const float*)d_in[3];
    const float* Wn0 = (const float*)d_in[4];
    const float* b0  = (const float*)d_in[5];
    const float* Ws1 = (const float*)d_in[6];
    const float* Wn1 = (const float*)d_in[7];
    const float* b1  = (const float*)d_in[8];
    const float* Ws2 = (const float*)d_in[9];
    const float* Wn2 = (const float*)d_in[10];
    const float* b2  = (const float*)d_in[11];
    float* out = (float*)d_out;

    char* ws = (char*)d_ws;
    size_t off = 0;
    auto alloc = [&](size_t bytes) -> void* {
        void* p = ws + off;
        off = (off + bytes + 255) & ~(size_t)255;
        return p;
    };
    int*   deg      = (int*)alloc((size_t)N_NODES * 4);
    int*   offs     = (int*)alloc((size_t)(N_NODES + 1) * 4);
    int*   pos      = (int*)alloc((size_t)N_NODES * 4);
    int*   edge_src = (int*)alloc((size_t)N_EDGES * 4);
    float* inv_deg  = (float*)alloc((size_t)N_NODES * 4);
    __hip_bfloat16* fbf = (__hip_bfloat16*)alloc((size_t)N_NODES * 128 * 2);
    __hip_bfloat16* msg = (__hip_bfloat16*)alloc((size_t)N_NODES * 128 * 2);
    __hip_bfloat16* h1  = (__hip_bfloat16*)alloc((size_t)N_NODES * 128 * 2);
    __hip_bfloat16* h2  = (__hip_bfloat16*)alloc((size_t)N_NODES * 128 * 2);
    __hip_bfloat16* frag0 = (__hip_bfloat16*)alloc((size_t)8 * 8 * 64 * 8 * 2);
    __hip_bfloat16* frag1 = (__hip_bfloat16*)alloc((size_t)8 * 8 * 64 * 8 * 2);
    __hip_bfloat16* frag2 = (__hip_bfloat16*)alloc((size_t)4 * 8 * 64 * 8 * 2);

    // CSR build
    k_zero<<<(N_NODES + 255) / 256, 256, 0, stream>>>(deg, N_NODES);
    k_deg<<<(N_EDGES + 255) / 256, 256, 0, stream>>>(dst, deg);
    k_scan<<<1, 1024, 0, stream>>>(deg, offs, pos, inv_deg);
    k_scatter<<<(N_EDGES + 255) / 256, 256, 0, stream>>>(src, dst, pos, edge_src);

    // features -> bf16 (once); W fragment packing
    const int n2 = N_NODES * 128 / 2;
    k_f2bf<<<(n2 + 255) / 256, 256, 0, stream>>>((const float2*)features, (unsigned int*)fbf, n2);
    k_wprep<<<16, 256, 0, stream>>>(Ws0, Wn0, 128, frag0);
    k_wprep<<<16, 256, 0, stream>>>(Ws1, Wn1, 128, frag1);
    k_wprep<<<8, 256, 0, stream>>>(Ws2, Wn2, 64, frag2);

    const int aggGrid = (N_NODES * 64) / 256;  // 12500
    const int gemmGrid = (N_NODES + 63) / 64;  // 782

    // Layer 1
    k_agg<<<aggGrid, 256, 0, stream>>>(fbf, offs, edge_src, inv_deg, msg);
    k_gemm<8, false><<<gemmGrid, 256, 0, stream>>>(fbf, msg, frag0, b0, h1);
    // Layer 2
    k_agg<<<aggGrid, 256, 0, stream>>>(h1, offs, edge_src, inv_deg, msg);
    k_gemm<8, false><<<gemmGrid, 256, 0, stream>>>(h1, msg, frag1, b1, h2);
    // Layer 3
    k_agg<<<aggGrid, 256, 0, stream>>>(h2, offs, edge_src, inv_deg, msg);
    k_gemm<4, true><<<gemmGrid, 256, 0, stream>>>(h2, msg, frag2, b2, out);
}

// Round 4
// 477.288 us; speedup vs baseline: 1.2532x; 1.2532x over previous
//
#include <hip/hip_runtime.h>
#include <hip/hip_bf16.h>

#define N_NODES 50000
#define N_EDGES 800000
#define SCAN_B 256
#define SCAN_NB ((N_NODES + SCAN_B - 1) / SCAN_B)  // 196

typedef __attribute__((ext_vector_type(8))) short bf16x8;
typedef __attribute__((ext_vector_type(4))) float f32x4;

__device__ __forceinline__ float bf2f(unsigned short u) {
    unsigned int x = ((unsigned int)u) << 16;
    return __uint_as_float(x);
}
__device__ __forceinline__ unsigned short f2bf(float f) {
    unsigned int x = __float_as_uint(f);
    unsigned int lsb = (x >> 16) & 1u;
    x += 0x7fffu + lsb;
    return (unsigned short)(x >> 16);
}

// ---------------- CSR build ----------------

__global__ void k_zero(int* p, int n) {
    int i = blockIdx.x * blockDim.x + threadIdx.x;
    if (i < n) p[i] = 0;
}

__global__ void k_deg(const int* __restrict__ dst, int* __restrict__ deg) {
    int e = blockIdx.x * blockDim.x + threadIdx.x;
    if (e < N_EDGES) atomicAdd(&deg[dst[e]], 1);
}

// hierarchical scan, stage 1: per-block sum (coalesced, whole GPU)
__global__ __launch_bounds__(SCAN_B) void k_scan1(const int* __restrict__ deg,
                                                  int* __restrict__ blocksum) {
    int i = blockIdx.x * SCAN_B + threadIdx.x;
    int v = (i < N_NODES) ? deg[i] : 0;
    #pragma unroll
    for (int d = 1; d < 64; d <<= 1) v += __shfl_xor(v, d);
    __shared__ int ws[SCAN_B / 64];
    int wv = threadIdx.x >> 6, lane = threadIdx.x & 63;
    if (lane == 0) ws[wv] = v;
    __syncthreads();
    if (threadIdx.x == 0) blocksum[blockIdx.x] = ws[0] + ws[1] + ws[2] + ws[3];
}

// stage 2: one small block scans the 196 block sums (8 barrier rounds)
__global__ __launch_bounds__(SCAN_B) void k_scan2(const int* __restrict__ blocksum,
                                                  int* __restrict__ blockoff,
                                                  int* __restrict__ offsets) {
    __shared__ int buf[SCAN_B];
    int tid = threadIdx.x;
    int v = (tid < SCAN_NB) ? blocksum[tid] : 0;
    buf[tid] = v;
    __syncthreads();
    for (int off = 1; off < SCAN_B; off <<= 1) {
        int t = (tid >= off) ? buf[tid - off] : 0;
        __syncthreads();
        buf[tid] += t;
        __syncthreads();
    }
    if (tid < SCAN_NB) blockoff[tid] = buf[tid] - v;  // exclusive
    if (tid == 0) offsets[N_NODES] = N_EDGES;         // total degree == E
}

// stage 3: per-block local scan (+ blockoff) -> offsets/pos/inv_deg
__global__ __launch_bounds__(SCAN_B) void k_scan3(const int* __restrict__ deg,
                                                  const int* __restrict__ blockoff,
                                                  int* __restrict__ offsets,
                                                  int* __restrict__ pos,
                                                  float* __restrict__ inv_deg) {
    int tid = threadIdx.x;
    int i = blockIdx.x * SCAN_B + tid;
    int v = (i < N_NODES) ? deg[i] : 0;
    int lane = tid & 63, wv = tid >> 6;
    int s = v;
    #pragma unroll
    for (int d = 1; d < 64; d <<= 1) {
        int t = __shfl_up(s, d);
        if (lane >= d) s += t;
    }
    __shared__ int wsum[SCAN_B / 64];
    if (lane == 63) wsum[wv] = s;
    __syncthreads();
    int add = 0;
    #pragma unroll
    for (int w = 0; w < SCAN_B / 64; ++w)
        if (w < wv) add += wsum[w];
    int excl = blockoff[blockIdx.x] + s + add - v;
    if (i < N_NODES) {
        offsets[i] = excl;
        pos[i] = excl;
        inv_deg[i] = 1.0f / (float)max(v, 1);
    }
}

__global__ void k_scatter(const int* __restrict__ src, const int* __restrict__ dst,
                          int* __restrict__ pos, int* __restrict__ edge_src) {
    int e = blockIdx.x * blockDim.x + threadIdx.x;
    if (e < N_EDGES) {
        int p = atomicAdd(&pos[dst[e]], 1);
        edge_src[p] = src[e];
    }
}

// ---------------- fp32 -> bf16 bulk convert (features, done once) ----------------
__global__ void k_f2bf(const float2* __restrict__ in, unsigned int* __restrict__ outp, int n2) {
    int i = blockIdx.x * blockDim.x + threadIdx.x;
    if (i < n2) {
        float2 v = in[i];
        outp[i] = ((unsigned int)f2bf(v.y) << 16) | (unsigned int)f2bf(v.x);
    }
}

// ---------------- mean aggregation (one wave per node) ----------------
// h: [N,128] bf16; lane i reads one packed uint (256B/row/wave). fp32 accumulation.
__global__ void k_agg(const __hip_bfloat16* __restrict__ hv, const int* __restrict__ offsets,
                      const int* __restrict__ edge_src, const float* __restrict__ inv_deg,
                      __hip_bfloat16* __restrict__ msg) {
    int gid = blockIdx.x * blockDim.x + threadIdx.x;
    int node = gid >> 6;
    int lane = gid & 63;
    if (node >= N_NODES) return;
    int beg = offsets[node], end = offsets[node + 1];
    float a0 = 0.f, a1 = 0.f;
    const unsigned int* hp = (const unsigned int*)hv;  // 64 uints per row
    for (int i = beg; i < end; ++i) {
        int s = edge_src[i];
        unsigned int u = hp[(size_t)s * 64 + lane];
        a0 += bf2f((unsigned short)(u & 0xffffu));
        a1 += bf2f((unsigned short)(u >> 16));
    }
    float w = inv_deg[node];
    unsigned int packed = ((unsigned int)f2bf(a1 * w) << 16) | (unsigned int)f2bf(a0 * w);
    ((unsigned int*)msg)[(size_t)node * 64 + lane] = packed;
}

// ---------------- W fragment packing (fp32 weights -> bf16 B-fragments) ----------------
// Bcat[k][n], k in [0,256): k<128 -> Wself[k][n], else Wneigh[k-128][n]. W row-major [128][Dout].
// frag: lane of (ct,kt) holds B[kt*32 + (lane>>4)*8 + j][ct*16 + (lane&15)], j=0..7.
__global__ void k_wprep(const float* __restrict__ Wself, const float* __restrict__ Wneigh,
                        int Dout, __hip_bfloat16* __restrict__ frag) {
    int t = blockIdx.x * blockDim.x + threadIdx.x;
    int nCt = Dout >> 4;
    int total = nCt * 8 * 64;
    if (t >= total) return;
    int lane = t & 63;
    int kt = (t >> 6) & 7;
    int ct = t >> 9;
    int q = lane >> 4;
    int n = ct * 16 + (lane & 15);
    unsigned short* dstp = (unsigned short*)frag + ((size_t)((ct * 8 + kt) * 64 + lane)) * 8;
    #pragma unroll
    for (int j = 0; j < 8; ++j) {
        int k = kt * 32 + q * 8 + j;
        float v = (k < 128) ? Wself[k * Dout + n] : Wneigh[(k - 128) * Dout + n];
        dstp[j] = f2bf(v);
    }
}

// ---------------- fused GEMM + bias (+ relu + l2norm) ----------------
// out[n][:] = epilogue( Aself[n]@Wself + Aneigh[n]@Wneigh + b ), K=256 fused via MFMA.
// Block = 256 threads = 4 waves; wave handles 16 rows x Dout cols.
// LAST: no relu/l2norm, output fp32; else output bf16.
template <int NCT, bool LAST>
__global__ __launch_bounds__(256) void k_gemm(const __hip_bfloat16* __restrict__ Aself,
                                              const __hip_bfloat16* __restrict__ Aneigh,
                                              const __hip_bfloat16* __restrict__ frag,
                                              const float* __restrict__ bias,
                                              void* __restrict__ out_) {
    constexpr int Dout = NCT * 16;
    int tid = threadIdx.x;
    int wv = tid >> 6, lane = tid & 63;
    int n0 = blockIdx.x * 64 + wv * 16;
    if (n0 >= N_NODES) return;  // wave-uniform early exit, no LDS used
    int q = lane >> 4, l15 = lane & 15;
    int rowA = n0 + l15;
    if (rowA > N_NODES - 1) rowA = N_NODES - 1;  // clamp loads; stores guarded below

    f32x4 acc[NCT];
    #pragma unroll
    for (int c = 0; c < NCT; ++c) acc[c] = (f32x4){0.f, 0.f, 0.f, 0.f};

    const bf16x8* fragv = (const bf16x8*)frag;
    #pragma unroll
    for (int kt = 0; kt < 8; ++kt) {
        int kb = (kt & 3) * 32 + q * 8;
        const __hip_bfloat16* Ab = (kt < 4) ? Aself : Aneigh;
        bf16x8 a = *(const bf16x8*)(Ab + (size_t)rowA * 128 + kb);
        #pragma unroll
        for (int ct = 0; ct < NCT; ++ct) {
            bf16x8 b = fragv[(ct * 8 + kt) * 64 + lane];
            acc[ct] = __builtin_amdgcn_mfma_f32_16x16x32_bf16(a, b, acc[ct], 0, 0, 0);
        }
    }

    float ss[4] = {0.f, 0.f, 0.f, 0.f};
    #pragma unroll
    for (int ct = 0; ct < NCT; ++ct) {
        float bc = bias[ct * 16 + l15];
        #pragma unroll
        for (int r = 0; r < 4; ++r) {
            float v = acc[ct][r] + bc;
            if (!LAST) v = fmaxf(v, 0.0f);
            acc[ct][r] = v;
            ss[r] += v * v;
        }
    }

    float scale[4];
    #pragma unroll
    for (int r = 0; r < 4; ++r) {
        if (!LAST) {
            float s = ss[r];
            s += __shfl_xor(s, 1);
            s += __shfl_xor(s, 2);
            s += __shfl_xor(s, 4);
            s += __shfl_xor(s, 8);
            scale[r] = 1.0f / fmaxf(sqrtf(s), 1e-12f);
        } else {
            scale[r] = 1.0f;
        }
    }

    #pragma unroll
    for (int ct = 0; ct < NCT; ++ct) {
        #pragma unroll
        for (int r = 0; r < 4; ++r) {
            int row = n0 + q * 4 + r;
            if (row < N_NODES) {
                float v = acc[ct][r] * scale[r];
                if (LAST)
                    ((float*)out_)[(size_t)row * Dout + ct * 16 + l15] = v;
                else
                    ((unsigned short*)out_)[(size_t)row * Dout + ct * 16 + l15] = f2bf(v);
            }
        }
    }
}

// ---------------- host launch ----------------

extern "C" void kernel_launch(void* const* d_in, const int* in_sizes, int n_in,
                              void* d_out, int out_size, void* d_ws, size_t ws_size,
                              hipStream_t stream) {
    const float* features = (const float*)d_in[0];
    const int* src = (const int*)d_in[1];
    const int* dst = (const int*)d_in[2];
    const float* Ws0 = (const float*)d_in[3];
    const float* Wn0 = (const float*)d_in[4];
    const float* b0  = (const float*)d_in[5];
    const float* Ws1 = (const float*)d_in[6];
    const float* Wn1 = (const float*)d_in[7];
    const float* b1  = (const float*)d_in[8];
    const float* Ws2 = (const float*)d_in[9];
    const float* Wn2 = (const float*)d_in[10];
    const float* b2  = (const float*)d_in[11];
    float* out = (float*)d_out;

    char* ws = (char*)d_ws;
    size_t off = 0;
    auto alloc = [&](size_t bytes) -> void* {
        void* p = ws + off;
        off = (off + bytes + 255) & ~(size_t)255;
        return p;
    };
    int*   deg      = (int*)alloc((size_t)N_NODES * 4);
    int*   offs     = (int*)alloc((size_t)(N_NODES + 1) * 4);
    int*   pos      = (int*)alloc((size_t)N_NODES * 4);
    int*   edge_src = (int*)alloc((size_t)N_EDGES * 4);
    float* inv_deg  = (float*)alloc((size_t)N_NODES * 4);
    int*   blocksum = (int*)alloc((size_t)SCAN_NB * 4);
    int*   blockoff = (int*)alloc((size_t)SCAN_NB * 4);
    __hip_bfloat16* fbf = (__hip_bfloat16*)alloc((size_t)N_NODES * 128 * 2);
    __hip_bfloat16* msg = (__hip_bfloat16*)alloc((size_t)N_NODES * 128 * 2);
    __hip_bfloat16* h1  = (__hip_bfloat16*)alloc((size_t)N_NODES * 128 * 2);
    __hip_bfloat16* h2  = (__hip_bfloat16*)alloc((size_t)N_NODES * 128 * 2);
    __hip_bfloat16* frag0 = (__hip_bfloat16*)alloc((size_t)8 * 8 * 64 * 8 * 2);
    __hip_bfloat16* frag1 = (__hip_bfloat16*)alloc((size_t)8 * 8 * 64 * 8 * 2);
    __hip_bfloat16* frag2 = (__hip_bfloat16*)alloc((size_t)4 * 8 * 64 * 8 * 2);

    // CSR build (parallel hierarchical scan)
    k_zero<<<(N_NODES + 255) / 256, 256, 0, stream>>>(deg, N_NODES);
    k_deg<<<(N_EDGES + 255) / 256, 256, 0, stream>>>(dst, deg);
    k_scan1<<<SCAN_NB, SCAN_B, 0, stream>>>(deg, blocksum);
    k_scan2<<<1, SCAN_B, 0, stream>>>(blocksum, blockoff, offs);
    k_scan3<<<SCAN_NB, SCAN_B, 0, stream>>>(deg, blockoff, offs, pos, inv_deg);
    k_scatter<<<(N_EDGES + 255) / 256, 256, 0, stream>>>(src, dst, pos, edge_src);

    // features -> bf16 (once); W fragment packing
    const int n2 = N_NODES * 128 / 2;
    k_f2bf<<<(n2 + 255) / 256, 256, 0, stream>>>((const float2*)features, (unsigned int*)fbf, n2);
    k_wprep<<<16, 256, 0, stream>>>(Ws0, Wn0, 128, frag0);
    k_wprep<<<16, 256, 0, stream>>>(Ws1, Wn1, 128, frag1);
    k_wprep<<<8, 256, 0, stream>>>(Ws2, Wn2, 64, frag2);

    const int aggGrid = (N_NODES * 64) / 256;  // 12500
    const int gemmGrid = (N_NODES + 63) / 64;  // 782

    // Layer 1
    k_agg<<<aggGrid, 256, 0, stream>>>(fbf, offs, edge_src, inv_deg, msg);
    k_gemm<8, false><<<gemmGrid, 256, 0, stream>>>(fbf, msg, frag0, b0, h1);
    // Layer 2
    k_agg<<<aggGrid, 256, 0, stream>>>(h1, offs, edge_src, inv_deg, msg);
    k_gemm<8, false><<<gemmGrid, 256, 0, stream>>>(h1, msg, frag1, b1, h2);
    // Layer 3
    k_agg<<<aggGrid, 256, 0, stream>>>(h2, offs, edge_src, inv_deg, msg);
    k_gemm<4, true><<<gemmGrid, 256, 0, stream>>>(h2, msg, frag2, b2, out);
}

// Round 5
// 349.379 us; speedup vs baseline: 1.7120x; 1.3661x over previous
//
#include <hip/hip_runtime.h>
#include <hip/hip_bf16.h>

#define N_NODES 50000
#define N_EDGES 800000
#define SCAN_B 256
#define SCAN_NB ((N_NODES + SCAN_B - 1) / SCAN_B)  // 196

typedef __attribute__((ext_vector_type(8))) short bf16x8;
typedef __attribute__((ext_vector_type(4))) float f32x4;

__device__ __forceinline__ float bf2f(unsigned short u) {
    unsigned int x = ((unsigned int)u) << 16;
    return __uint_as_float(x);
}
__device__ __forceinline__ unsigned short f2bf(float f) {
    unsigned int x = __float_as_uint(f);
    unsigned int lsb = (x >> 16) & 1u;
    x += 0x7fffu + lsb;
    return (unsigned short)(x >> 16);
}

// ---------------- CSR build ----------------

__global__ void k_zero(int* p, int n) {
    int i = blockIdx.x * blockDim.x + threadIdx.x;
    if (i < n) p[i] = 0;
}

__global__ void k_deg(const int* __restrict__ dst, int* __restrict__ deg) {
    int e = blockIdx.x * blockDim.x + threadIdx.x;
    if (e < N_EDGES) atomicAdd(&deg[dst[e]], 1);
}

// hierarchical scan, stage 1: per-block sum (coalesced, whole GPU)
__global__ __launch_bounds__(SCAN_B) void k_scan1(const int* __restrict__ deg,
                                                  int* __restrict__ blocksum) {
    int i = blockIdx.x * SCAN_B + threadIdx.x;
    int v = (i < N_NODES) ? deg[i] : 0;
    #pragma unroll
    for (int d = 1; d < 64; d <<= 1) v += __shfl_xor(v, d);
    __shared__ int ws[SCAN_B / 64];
    int wv = threadIdx.x >> 6, lane = threadIdx.x & 63;
    if (lane == 0) ws[wv] = v;
    __syncthreads();
    if (threadIdx.x == 0) blocksum[blockIdx.x] = ws[0] + ws[1] + ws[2] + ws[3];
}

// stage 2: one small block scans the 196 block sums (8 barrier rounds)
__global__ __launch_bounds__(SCAN_B) void k_scan2(const int* __restrict__ blocksum,
                                                  int* __restrict__ blockoff,
                                                  int* __restrict__ offsets) {
    __shared__ int buf[SCAN_B];
    int tid = threadIdx.x;
    int v = (tid < SCAN_NB) ? blocksum[tid] : 0;
    buf[tid] = v;
    __syncthreads();
    for (int off = 1; off < SCAN_B; off <<= 1) {
        int t = (tid >= off) ? buf[tid - off] : 0;
        __syncthreads();
        buf[tid] += t;
        __syncthreads();
    }
    if (tid < SCAN_NB) blockoff[tid] = buf[tid] - v;  // exclusive
    if (tid == 0) offsets[N_NODES] = N_EDGES;         // total degree == E
}

// stage 3: per-block local scan (+ blockoff) -> offsets/pos/inv_deg
__global__ __launch_bounds__(SCAN_B) void k_scan3(const int* __restrict__ deg,
                                                  const int* __restrict__ blockoff,
                                                  int* __restrict__ offsets,
                                                  int* __restrict__ pos,
                                                  float* __restrict__ inv_deg) {
    int tid = threadIdx.x;
    int i = blockIdx.x * SCAN_B + tid;
    int v = (i < N_NODES) ? deg[i] : 0;
    int lane = tid & 63, wv = tid >> 6;
    int s = v;
    #pragma unroll
    for (int d = 1; d < 64; d <<= 1) {
        int t = __shfl_up(s, d);
        if (lane >= d) s += t;
    }
    __shared__ int wsum[SCAN_B / 64];
    if (lane == 63) wsum[wv] = s;
    __syncthreads();
    int add = 0;
    #pragma unroll
    for (int w = 0; w < SCAN_B / 64; ++w)
        if (w < wv) add += wsum[w];
    int excl = blockoff[blockIdx.x] + s + add - v;
    if (i < N_NODES) {
        offsets[i] = excl;
        pos[i] = excl;
        inv_deg[i] = 1.0f / (float)max(v, 1);
    }
}

__global__ void k_scatter(const int* __restrict__ src, const int* __restrict__ dst,
                          int* __restrict__ pos, int* __restrict__ edge_src) {
    int e = blockIdx.x * blockDim.x + threadIdx.x;
    if (e < N_EDGES) {
        int p = atomicAdd(&pos[dst[e]], 1);
        edge_src[p] = src[e];
    }
}

// ---------------- fp32 -> bf16 bulk convert (features, done once) ----------------
__global__ void k_f2bf(const float2* __restrict__ in, unsigned int* __restrict__ outp, int n2) {
    int i = blockIdx.x * blockDim.x + threadIdx.x;
    if (i < n2) {
        float2 v = in[i];
        outp[i] = ((unsigned int)f2bf(v.y) << 16) | (unsigned int)f2bf(v.x);
    }
}

// ---------------- mean aggregation (one wave per node, 4x-unrolled MLP) ----------------
// h: [N,128] bf16; lane i reads one packed uint (256B/row/wave). fp32 accumulation.
// 4 independent gathers in flight per wave (latency-bound fix: R4 showed ~1
// outstanding 256B gather/wave = 1.4MB in flight vs ~3.8MB needed for BW sat).
__global__ void k_agg(const __hip_bfloat16* __restrict__ hv, const int* __restrict__ offsets,
                      const int* __restrict__ edge_src, const float* __restrict__ inv_deg,
                      __hip_bfloat16* __restrict__ msg) {
    int gid = blockIdx.x * blockDim.x + threadIdx.x;
    int node = gid >> 6;
    int lane = gid & 63;
    if (node >= N_NODES) return;
    int beg = offsets[node], end = offsets[node + 1];
    const unsigned int* hp = (const unsigned int*)hv;  // 64 uints per row
    float a0 = 0.f, a1 = 0.f, b0 = 0.f, b1 = 0.f;
    float c0 = 0.f, c1 = 0.f, d0 = 0.f, d1 = 0.f;
    int i = beg;
    for (; i + 4 <= end; i += 4) {
        int s0 = edge_src[i];
        int s1 = edge_src[i + 1];
        int s2 = edge_src[i + 2];
        int s3 = edge_src[i + 3];
        unsigned int u0 = hp[(size_t)s0 * 64 + lane];
        unsigned int u1 = hp[(size_t)s1 * 64 + lane];
        unsigned int u2 = hp[(size_t)s2 * 64 + lane];
        unsigned int u3 = hp[(size_t)s3 * 64 + lane];
        a0 += bf2f((unsigned short)(u0 & 0xffffu)); a1 += bf2f((unsigned short)(u0 >> 16));
        b0 += bf2f((unsigned short)(u1 & 0xffffu)); b1 += bf2f((unsigned short)(u1 >> 16));
        c0 += bf2f((unsigned short)(u2 & 0xffffu)); c1 += bf2f((unsigned short)(u2 >> 16));
        d0 += bf2f((unsigned short)(u3 & 0xffffu)); d1 += bf2f((unsigned short)(u3 >> 16));
    }
    for (; i < end; ++i) {
        int s = edge_src[i];
        unsigned int u = hp[(size_t)s * 64 + lane];
        a0 += bf2f((unsigned short)(u & 0xffffu));
        a1 += bf2f((unsigned short)(u >> 16));
    }
    a0 += b0 + c0 + d0;
    a1 += b1 + c1 + d1;
    float w = inv_deg[node];
    unsigned int packed = ((unsigned int)f2bf(a1 * w) << 16) | (unsigned int)f2bf(a0 * w);
    ((unsigned int*)msg)[(size_t)node * 64 + lane] = packed;
}

// ---------------- W fragment packing (fp32 weights -> bf16 B-fragments) ----------------
// Bcat[k][n], k in [0,256): k<128 -> Wself[k][n], else Wneigh[k-128][n]. W row-major [128][Dout].
// frag: lane of (ct,kt) holds B[kt*32 + (lane>>4)*8 + j][ct*16 + (lane&15)], j=0..7.
__global__ void k_wprep(const float* __restrict__ Wself, const float* __restrict__ Wneigh,
                        int Dout, __hip_bfloat16* __restrict__ frag) {
    int t = blockIdx.x * blockDim.x + threadIdx.x;
    int nCt = Dout >> 4;
    int total = nCt * 8 * 64;
    if (t >= total) return;
    int lane = t & 63;
    int kt = (t >> 6) & 7;
    int ct = t >> 9;
    int q = lane >> 4;
    int n = ct * 16 + (lane & 15);
    unsigned short* dstp = (unsigned short*)frag + ((size_t)((ct * 8 + kt) * 64 + lane)) * 8;
    #pragma unroll
    for (int j = 0; j < 8; ++j) {
        int k = kt * 32 + q * 8 + j;
        float v = (k < 128) ? Wself[k * Dout + n] : Wneigh[(k - 128) * Dout + n];
        dstp[j] = f2bf(v);
    }
}

// ---------------- fused GEMM + bias (+ relu + l2norm) ----------------
// out[n][:] = epilogue( Aself[n]@Wself + Aneigh[n]@Wneigh + b ), K=256 fused via MFMA.
// Block = 256 threads = 4 waves; wave handles 16 rows x Dout cols.
// LAST: no relu/l2norm, output fp32; else output bf16.
template <int NCT, bool LAST>
__global__ __launch_bounds__(256) void k_gemm(const __hip_bfloat16* __restrict__ Aself,
                                              const __hip_bfloat16* __restrict__ Aneigh,
                                              const __hip_bfloat16* __restrict__ frag,
                                              const float* __restrict__ bias,
                                              void* __restrict__ out_) {
    constexpr int Dout = NCT * 16;
    int tid = threadIdx.x;
    int wv = tid >> 6, lane = tid & 63;
    int n0 = blockIdx.x * 64 + wv * 16;
    if (n0 >= N_NODES) return;  // wave-uniform early exit, no LDS used
    int q = lane >> 4, l15 = lane & 15;
    int rowA = n0 + l15;
    if (rowA > N_NODES - 1) rowA = N_NODES - 1;  // clamp loads; stores guarded below

    f32x4 acc[NCT];
    #pragma unroll
    for (int c = 0; c < NCT; ++c) acc[c] = (f32x4){0.f, 0.f, 0.f, 0.f};

    const bf16x8* fragv = (const bf16x8*)frag;
    #pragma unroll
    for (int kt = 0; kt < 8; ++kt) {
        int kb = (kt & 3) * 32 + q * 8;
        const __hip_bfloat16* Ab = (kt < 4) ? Aself : Aneigh;
        bf16x8 a = *(const bf16x8*)(Ab + (size_t)rowA * 128 + kb);
        #pragma unroll
        for (int ct = 0; ct < NCT; ++ct) {
            bf16x8 b = fragv[(ct * 8 + kt) * 64 + lane];
            acc[ct] = __builtin_amdgcn_mfma_f32_16x16x32_bf16(a, b, acc[ct], 0, 0, 0);
        }
    }

    float ss[4] = {0.f, 0.f, 0.f, 0.f};
    #pragma unroll
    for (int ct = 0; ct < NCT; ++ct) {
        float bc = bias[ct * 16 + l15];
        #pragma unroll
        for (int r = 0; r < 4; ++r) {
            float v = acc[ct][r] + bc;
            if (!LAST) v = fmaxf(v, 0.0f);
            acc[ct][r] = v;
            ss[r] += v * v;
        }
    }

    float scale[4];
    #pragma unroll
    for (int r = 0; r < 4; ++r) {
        if (!LAST) {
            float s = ss[r];
            s += __shfl_xor(s, 1);
            s += __shfl_xor(s, 2);
            s += __shfl_xor(s, 4);
            s += __shfl_xor(s, 8);
            scale[r] = 1.0f / fmaxf(sqrtf(s), 1e-12f);
        } else {
            scale[r] = 1.0f;
        }
    }

    #pragma unroll
    for (int ct = 0; ct < NCT; ++ct) {
        #pragma unroll
        for (int r = 0; r < 4; ++r) {
            int row = n0 + q * 4 + r;
            if (row < N_NODES) {
                float v = acc[ct][r] * scale[r];
                if (LAST)
                    ((float*)out_)[(size_t)row * Dout + ct * 16 + l15] = v;
                else
                    ((unsigned short*)out_)[(size_t)row * Dout + ct * 16 + l15] = f2bf(v);
            }
        }
    }
}

// ---------------- host launch ----------------

extern "C" void kernel_launch(void* const* d_in, const int* in_sizes, int n_in,
                              void* d_out, int out_size, void* d_ws, size_t ws_size,
                              hipStream_t stream) {
    const float* features = (const float*)d_in[0];
    const int* src = (const int*)d_in[1];
    const int* dst = (const int*)d_in[2];
    const float* Ws0 = (const float*)d_in[3];
    const float* Wn0 = (const float*)d_in[4];
    const float* b0  = (const float*)d_in[5];
    const float* Ws1 = (const float*)d_in[6];
    const float* Wn1 = (const float*)d_in[7];
    const float* b1  = (const float*)d_in[8];
    const float* Ws2 = (const float*)d_in[9];
    const float* Wn2 = (const float*)d_in[10];
    const float* b2  = (const float*)d_in[11];
    float* out = (float*)d_out;

    char* ws = (char*)d_ws;
    size_t off = 0;
    auto alloc = [&](size_t bytes) -> void* {
        void* p = ws + off;
        off = (off + bytes + 255) & ~(size_t)255;
        return p;
    };
    int*   deg      = (int*)alloc((size_t)N_NODES * 4);
    int*   offs     = (int*)alloc((size_t)(N_NODES + 1) * 4);
    int*   pos      = (int*)alloc((size_t)N_NODES * 4);
    int*   edge_src = (int*)alloc((size_t)N_EDGES * 4);
    float* inv_deg  = (float*)alloc((size_t)N_NODES * 4);
    int*   blocksum = (int*)alloc((size_t)SCAN_NB * 4);
    int*   blockoff = (int*)alloc((size_t)SCAN_NB * 4);
    __hip_bfloat16* fbf = (__hip_bfloat16*)alloc((size_t)N_NODES * 128 * 2);
    __hip_bfloat16* msg = (__hip_bfloat16*)alloc((size_t)N_NODES * 128 * 2);
    __hip_bfloat16* h1  = (__hip_bfloat16*)alloc((size_t)N_NODES * 128 * 2);
    __hip_bfloat16* h2  = (__hip_bfloat16*)alloc((size_t)N_NODES * 128 * 2);
    __hip_bfloat16* frag0 = (__hip_bfloat16*)alloc((size_t)8 * 8 * 64 * 8 * 2);
    __hip_bfloat16* frag1 = (__hip_bfloat16*)alloc((size_t)8 * 8 * 64 * 8 * 2);
    __hip_bfloat16* frag2 = (__hip_bfloat16*)alloc((size_t)4 * 8 * 64 * 8 * 2);

    // CSR build (parallel hierarchical scan)
    k_zero<<<(N_NODES + 255) / 256, 256, 0, stream>>>(deg, N_NODES);
    k_deg<<<(N_EDGES + 255) / 256, 256, 0, stream>>>(dst, deg);
    k_scan1<<<SCAN_NB, SCAN_B, 0, stream>>>(deg, blocksum);
    k_scan2<<<1, SCAN_B, 0, stream>>>(blocksum, blockoff, offs);
    k_scan3<<<SCAN_NB, SCAN_B, 0, stream>>>(deg, blockoff, offs, pos, inv_deg);
    k_scatter<<<(N_EDGES + 255) / 256, 256, 0, stream>>>(src, dst, pos, edge_src);

    // features -> bf16 (once); W fragment packing
    const int n2 = N_NODES * 128 / 2;
    k_f2bf<<<(n2 + 255) / 256, 256, 0, stream>>>((const float2*)features, (unsigned int*)fbf, n2);
    k_wprep<<<16, 256, 0, stream>>>(Ws0, Wn0, 128, frag0);
    k_wprep<<<16, 256, 0, stream>>>(Ws1, Wn1, 128, frag1);
    k_wprep<<<8, 256, 0, stream>>>(Ws2, Wn2, 64, frag2);

    const int aggGrid = (N_NODES * 64) / 256;  // 12500
    const int gemmGrid = (N_NODES + 63) / 64;  // 782

    // Layer 1
    k_agg<<<aggGrid, 256, 0, stream>>>(fbf, offs, edge_src, inv_deg, msg);
    k_gemm<8, false><<<gemmGrid, 256, 0, stream>>>(fbf, msg, frag0, b0, h1);
    // Layer 2
    k_agg<<<aggGrid, 256, 0, stream>>>(h1, offs, edge_src, inv_deg, msg);
    k_gemm<8, false><<<gemmGrid, 256, 0, stream>>>(h1, msg, frag1, b1, h2);
    // Layer 3
    k_agg<<<aggGrid, 256, 0, stream>>>(h2, offs, edge_src, inv_deg, msg);
    k_gemm<4, true><<<gemmGrid, 256, 0, stream>>>(h2, msg, frag2, b2, out);
}

// Round 6
// 327.295 us; speedup vs baseline: 1.8275x; 1.0675x over previous
//
#include <hip/hip_runtime.h>
#include <hip/hip_bf16.h>

#define N_NODES 50000
#define N_EDGES 800000
#define SCAN_B 256
#define SCAN_NB ((N_NODES + SCAN_B - 1) / SCAN_B)  // 196

typedef __attribute__((ext_vector_type(8))) short bf16x8;
typedef __attribute__((ext_vector_type(4))) float f32x4;

__device__ __forceinline__ float bf2f(unsigned short u) {
    unsigned int x = ((unsigned int)u) << 16;
    return __uint_as_float(x);
}
__device__ __forceinline__ unsigned short f2bf(float f) {
    unsigned int x = __float_as_uint(f);
    unsigned int lsb = (x >> 16) & 1u;
    x += 0x7fffu + lsb;
    return (unsigned short)(x >> 16);
}

// ---------------- CSR build ----------------

__global__ void k_zero(int* p, int n) {
    int i = blockIdx.x * blockDim.x + threadIdx.x;
    if (i < n) p[i] = 0;
}

__global__ void k_deg(const int* __restrict__ dst, int* __restrict__ deg) {
    int e = blockIdx.x * blockDim.x + threadIdx.x;
    if (e < N_EDGES) atomicAdd(&deg[dst[e]], 1);
}

// hierarchical scan, stage 1: per-block sum (coalesced, whole GPU)
__global__ __launch_bounds__(SCAN_B) void k_scan1(const int* __restrict__ deg,
                                                  int* __restrict__ blocksum) {
    int i = blockIdx.x * SCAN_B + threadIdx.x;
    int v = (i < N_NODES) ? deg[i] : 0;
    #pragma unroll
    for (int d = 1; d < 64; d <<= 1) v += __shfl_xor(v, d);
    __shared__ int ws[SCAN_B / 64];
    int wv = threadIdx.x >> 6, lane = threadIdx.x & 63;
    if (lane == 0) ws[wv] = v;
    __syncthreads();
    if (threadIdx.x == 0) blocksum[blockIdx.x] = ws[0] + ws[1] + ws[2] + ws[3];
}

// stage 2: one small block scans the 196 block sums (8 barrier rounds)
__global__ __launch_bounds__(SCAN_B) void k_scan2(const int* __restrict__ blocksum,
                                                  int* __restrict__ blockoff,
                                                  int* __restrict__ offsets) {
    __shared__ int buf[SCAN_B];
    int tid = threadIdx.x;
    int v = (tid < SCAN_NB) ? blocksum[tid] : 0;
    buf[tid] = v;
    __syncthreads();
    for (int off = 1; off < SCAN_B; off <<= 1) {
        int t = (tid >= off) ? buf[tid - off] : 0;
        __syncthreads();
        buf[tid] += t;
        __syncthreads();
    }
    if (tid < SCAN_NB) blockoff[tid] = buf[tid] - v;  // exclusive
    if (tid == 0) offsets[N_NODES] = N_EDGES;         // total degree == E
}

// stage 3: per-block local scan (+ blockoff) -> offsets/pos/inv_deg
__global__ __launch_bounds__(SCAN_B) void k_scan3(const int* __restrict__ deg,
                                                  const int* __restrict__ blockoff,
                                                  int* __restrict__ offsets,
                                                  int* __restrict__ pos,
                                                  float* __restrict__ inv_deg) {
    int tid = threadIdx.x;
    int i = blockIdx.x * SCAN_B + tid;
    int v = (i < N_NODES) ? deg[i] : 0;
    int lane = tid & 63, wv = tid >> 6;
    int s = v;
    #pragma unroll
    for (int d = 1; d < 64; d <<= 1) {
        int t = __shfl_up(s, d);
        if (lane >= d) s += t;
    }
    __shared__ int wsum[SCAN_B / 64];
    if (lane == 63) wsum[wv] = s;
    __syncthreads();
    int add = 0;
    #pragma unroll
    for (int w = 0; w < SCAN_B / 64; ++w)
        if (w < wv) add += wsum[w];
    int excl = blockoff[blockIdx.x] + s + add - v;
    if (i < N_NODES) {
        offsets[i] = excl;
        pos[i] = excl;
        inv_deg[i] = 1.0f / (float)max(v, 1);
    }
}

__global__ void k_scatter(const int* __restrict__ src, const int* __restrict__ dst,
                          int* __restrict__ pos, int* __restrict__ edge_src) {
    int e = blockIdx.x * blockDim.x + threadIdx.x;
    if (e < N_EDGES) {
        int p = atomicAdd(&pos[dst[e]], 1);
        edge_src[p] = src[e];
    }
}

// ---------------- fp32 -> bf16 bulk convert (features, done once) ----------------
__global__ void k_f2bf(const float2* __restrict__ in, unsigned int* __restrict__ outp, int n2) {
    int i = blockIdx.x * blockDim.x + threadIdx.x;
    if (i < n2) {
        float2 v = in[i];
        outp[i] = ((unsigned int)f2bf(v.y) << 16) | (unsigned int)f2bf(v.x);
    }
}

// ---------------- mean aggregation (one wave per node, half-wave edge pairs) ----------------
// h: [N,128] bf16. Lane (half, sub): half=lane>>5 picks the edge parity, sub=lane&31
// owns cols [4*sub..4*sub+3] via one dwordx2. Main loop: 8 edges/iter with 4
// independent 8B gathers in flight per lane (2KB/wave — 2x R5's MLP).
// Cross-half combine via shfl_xor(32) at the end. fp32 accumulation.
__global__ void k_agg(const __hip_bfloat16* __restrict__ hv, const int* __restrict__ offsets,
                      const int* __restrict__ edge_src, const float* __restrict__ inv_deg,
                      __hip_bfloat16* __restrict__ msg) {
    int gid = blockIdx.x * blockDim.x + threadIdx.x;
    int node = gid >> 6;
    int lane = gid & 63;
    if (node >= N_NODES) return;
    int half = lane >> 5;
    int sub = lane & 31;
    int beg = offsets[node], end = offsets[node + 1];
    const uint2* hp = (const uint2*)hv;  // 32 uint2 per row

    float acc[4][4];
    #pragma unroll
    for (int g = 0; g < 4; ++g)
        #pragma unroll
        for (int c = 0; c < 4; ++c) acc[g][c] = 0.f;

    int i = beg;
    for (; i + 8 <= end; i += 8) {
        int s0 = edge_src[i + half];
        int s1 = edge_src[i + 2 + half];
        int s2 = edge_src[i + 4 + half];
        int s3 = edge_src[i + 6 + half];
        uint2 u0 = hp[(size_t)s0 * 32 + sub];
        uint2 u1 = hp[(size_t)s1 * 32 + sub];
        uint2 u2 = hp[(size_t)s2 * 32 + sub];
        uint2 u3 = hp[(size_t)s3 * 32 + sub];
        acc[0][0] += bf2f((unsigned short)(u0.x & 0xffffu)); acc[0][1] += bf2f((unsigned short)(u0.x >> 16));
        acc[0][2] += bf2f((unsigned short)(u0.y & 0xffffu)); acc[0][3] += bf2f((unsigned short)(u0.y >> 16));
        acc[1][0] += bf2f((unsigned short)(u1.x & 0xffffu)); acc[1][1] += bf2f((unsigned short)(u1.x >> 16));
        acc[1][2] += bf2f((unsigned short)(u1.y & 0xffffu)); acc[1][3] += bf2f((unsigned short)(u1.y >> 16));
        acc[2][0] += bf2f((unsigned short)(u2.x & 0xffffu)); acc[2][1] += bf2f((unsigned short)(u2.x >> 16));
        acc[2][2] += bf2f((unsigned short)(u2.y & 0xffffu)); acc[2][3] += bf2f((unsigned short)(u2.y >> 16));
        acc[3][0] += bf2f((unsigned short)(u3.x & 0xffffu)); acc[3][1] += bf2f((unsigned short)(u3.x >> 16));
        acc[3][2] += bf2f((unsigned short)(u3.y & 0xffffu)); acc[3][3] += bf2f((unsigned short)(u3.y >> 16));
    }
    for (; i + 4 <= end; i += 4) {
        int s0 = edge_src[i + half];
        int s1 = edge_src[i + 2 + half];
        uint2 u0 = hp[(size_t)s0 * 32 + sub];
        uint2 u1 = hp[(size_t)s1 * 32 + sub];
        acc[0][0] += bf2f((unsigned short)(u0.x & 0xffffu)); acc[0][1] += bf2f((unsigned short)(u0.x >> 16));
        acc[0][2] += bf2f((unsigned short)(u0.y & 0xffffu)); acc[0][3] += bf2f((unsigned short)(u0.y >> 16));
        acc[1][0] += bf2f((unsigned short)(u1.x & 0xffffu)); acc[1][1] += bf2f((unsigned short)(u1.x >> 16));
        acc[1][2] += bf2f((unsigned short)(u1.y & 0xffffu)); acc[1][3] += bf2f((unsigned short)(u1.y >> 16));
    }
    for (; i + 2 <= end; i += 2) {
        int s0 = edge_src[i + half];
        uint2 u0 = hp[(size_t)s0 * 32 + sub];
        acc[0][0] += bf2f((unsigned short)(u0.x & 0xffffu)); acc[0][1] += bf2f((unsigned short)(u0.x >> 16));
        acc[0][2] += bf2f((unsigned short)(u0.y & 0xffffu)); acc[0][3] += bf2f((unsigned short)(u0.y >> 16));
    }
    if (i < end && half == 0) {  // odd leftover: half 0 only
        int s0 = edge_src[i];
        uint2 u0 = hp[(size_t)s0 * 32 + sub];
        acc[0][0] += bf2f((unsigned short)(u0.x & 0xffffu)); acc[0][1] += bf2f((unsigned short)(u0.x >> 16));
        acc[0][2] += bf2f((unsigned short)(u0.y & 0xffffu)); acc[0][3] += bf2f((unsigned short)(u0.y >> 16));
    }

    float r0 = acc[0][0] + acc[1][0] + acc[2][0] + acc[3][0];
    float r1 = acc[0][1] + acc[1][1] + acc[2][1] + acc[3][1];
    float r2 = acc[0][2] + acc[1][2] + acc[2][2] + acc[3][2];
    float r3 = acc[0][3] + acc[1][3] + acc[2][3] + acc[3][3];
    r0 += __shfl_xor(r0, 32);
    r1 += __shfl_xor(r1, 32);
    r2 += __shfl_xor(r2, 32);
    r3 += __shfl_xor(r3, 32);
    if (half == 0) {
        float w = inv_deg[node];
        uint2 o;
        o.x = ((unsigned int)f2bf(r1 * w) << 16) | (unsigned int)f2bf(r0 * w);
        o.y = ((unsigned int)f2bf(r3 * w) << 16) | (unsigned int)f2bf(r2 * w);
        ((uint2*)msg)[(size_t)node * 32 + sub] = o;
    }
}

// ---------------- W fragment packing (fp32 weights -> bf16 B-fragments) ----------------
// Bcat[k][n], k in [0,256): k<128 -> Wself[k][n], else Wneigh[k-128][n]. W row-major [128][Dout].
// frag: lane of (ct,kt) holds B[kt*32 + (lane>>4)*8 + j][ct*16 + (lane&15)], j=0..7.
__global__ void k_wprep(const float* __restrict__ Wself, const float* __restrict__ Wneigh,
                        int Dout, __hip_bfloat16* __restrict__ frag) {
    int t = blockIdx.x * blockDim.x + threadIdx.x;
    int nCt = Dout >> 4;
    int total = nCt * 8 * 64;
    if (t >= total) return;
    int lane = t & 63;
    int kt = (t >> 6) & 7;
    int ct = t >> 9;
    int q = lane >> 4;
    int n = ct * 16 + (lane & 15);
    unsigned short* dstp = (unsigned short*)frag + ((size_t)((ct * 8 + kt) * 64 + lane)) * 8;
    #pragma unroll
    for (int j = 0; j < 8; ++j) {
        int k = kt * 32 + q * 8 + j;
        float v = (k < 128) ? Wself[k * Dout + n] : Wneigh[(k - 128) * Dout + n];
        dstp[j] = f2bf(v);
    }
}

// ---------------- fused GEMM + bias (+ relu + l2norm) ----------------
// out[n][:] = epilogue( Aself[n]@Wself + Aneigh[n]@Wneigh + b ), K=256 fused via MFMA.
// Block = 256 threads = 4 waves; wave handles 16 rows x Dout cols.
// LAST: no relu/l2norm, output fp32; else output bf16.
template <int NCT, bool LAST>
__global__ __launch_bounds__(256) void k_gemm(const __hip_bfloat16* __restrict__ Aself,
                                              const __hip_bfloat16* __restrict__ Aneigh,
                                              const __hip_bfloat16* __restrict__ frag,
                                              const float* __restrict__ bias,
                                              void* __restrict__ out_) {
    constexpr int Dout = NCT * 16;
    int tid = threadIdx.x;
    int wv = tid >> 6, lane = tid & 63;
    int n0 = blockIdx.x * 64 + wv * 16;
    if (n0 >= N_NODES) return;  // wave-uniform early exit, no LDS used
    int q = lane >> 4, l15 = lane & 15;
    int rowA = n0 + l15;
    if (rowA > N_NODES - 1) rowA = N_NODES - 1;  // clamp loads; stores guarded below

    f32x4 acc[NCT];
    #pragma unroll
    for (int c = 0; c < NCT; ++c) acc[c] = (f32x4){0.f, 0.f, 0.f, 0.f};

    const bf16x8* fragv = (const bf16x8*)frag;
    #pragma unroll
    for (int kt = 0; kt < 8; ++kt) {
        int kb = (kt & 3) * 32 + q * 8;
        const __hip_bfloat16* Ab = (kt < 4) ? Aself : Aneigh;
        bf16x8 a = *(const bf16x8*)(Ab + (size_t)rowA * 128 + kb);
        #pragma unroll
        for (int ct = 0; ct < NCT; ++ct) {
            bf16x8 b = fragv[(ct * 8 + kt) * 64 + lane];
            acc[ct] = __builtin_amdgcn_mfma_f32_16x16x32_bf16(a, b, acc[ct], 0, 0, 0);
        }
    }

    float ss[4] = {0.f, 0.f, 0.f, 0.f};
    #pragma unroll
    for (int ct = 0; ct < NCT; ++ct) {
        float bc = bias[ct * 16 + l15];
        #pragma unroll
        for (int r = 0; r < 4; ++r) {
            float v = acc[ct][r] + bc;
            if (!LAST) v = fmaxf(v, 0.0f);
            acc[ct][r] = v;
            ss[r] += v * v;
        }
    }

    float scale[4];
    #pragma unroll
    for (int r = 0; r < 4; ++r) {
        if (!LAST) {
            float s = ss[r];
            s += __shfl_xor(s, 1);
            s += __shfl_xor(s, 2);
            s += __shfl_xor(s, 4);
            s += __shfl_xor(s, 8);
            scale[r] = 1.0f / fmaxf(sqrtf(s), 1e-12f);
        } else {
            scale[r] = 1.0f;
        }
    }

    #pragma unroll
    for (int ct = 0; ct < NCT; ++ct) {
        #pragma unroll
        for (int r = 0; r < 4; ++r) {
            int row = n0 + q * 4 + r;
            if (row < N_NODES) {
                float v = acc[ct][r] * scale[r];
                if (LAST)
                    ((float*)out_)[(size_t)row * Dout + ct * 16 + l15] = v;
                else
                    ((unsigned short*)out_)[(size_t)row * Dout + ct * 16 + l15] = f2bf(v);
            }
        }
    }
}

// ---------------- host launch ----------------

extern "C" void kernel_launch(void* const* d_in, const int* in_sizes, int n_in,
                              void* d_out, int out_size, void* d_ws, size_t ws_size,
                              hipStream_t stream) {
    const float* features = (const float*)d_in[0];
    const int* src = (const int*)d_in[1];
    const int* dst = (const int*)d_in[2];
    const float* Ws0 = (const float*)d_in[3];
    const float* Wn0 = (const float*)d_in[4];
    const float* b0  = (const float*)d_in[5];
    const float* Ws1 = (const float*)d_in[6];
    const float* Wn1 = (const float*)d_in[7];
    const float* b1  = (const float*)d_in[8];
    const float* Ws2 = (const float*)d_in[9];
    const float* Wn2 = (const float*)d_in[10];
    const float* b2  = (const float*)d_in[11];
    float* out = (float*)d_out;

    char* ws = (char*)d_ws;
    size_t off = 0;
    auto alloc = [&](size_t bytes) -> void* {
        void* p = ws + off;
        off = (off + bytes + 255) & ~(size_t)255;
        return p;
    };
    int*   deg      = (int*)alloc((size_t)N_NODES * 4);
    int*   offs     = (int*)alloc((size_t)(N_NODES + 1) * 4);
    int*   pos      = (int*)alloc((size_t)N_NODES * 4);
    int*   edge_src = (int*)alloc((size_t)N_EDGES * 4);
    float* inv_deg  = (float*)alloc((size_t)N_NODES * 4);
    int*   blocksum = (int*)alloc((size_t)SCAN_NB * 4);
    int*   blockoff = (int*)alloc((size_t)SCAN_NB * 4);
    __hip_bfloat16* fbf = (__hip_bfloat16*)alloc((size_t)N_NODES * 128 * 2);
    __hip_bfloat16* msg = (__hip_bfloat16*)alloc((size_t)N_NODES * 128 * 2);
    __hip_bfloat16* h1  = (__hip_bfloat16*)alloc((size_t)N_NODES * 128 * 2);
    __hip_bfloat16* h2  = (__hip_bfloat16*)alloc((size_t)N_NODES * 128 * 2);
    __hip_bfloat16* frag0 = (__hip_bfloat16*)alloc((size_t)8 * 8 * 64 * 8 * 2);
    __hip_bfloat16* frag1 = (__hip_bfloat16*)alloc((size_t)8 * 8 * 64 * 8 * 2);
    __hip_bfloat16* frag2 = (__hip_bfloat16*)alloc((size_t)4 * 8 * 64 * 8 * 2);

    // CSR build (parallel hierarchical scan)
    k_zero<<<(N_NODES + 255) / 256, 256, 0, stream>>>(deg, N_NODES);
    k_deg<<<(N_EDGES + 255) / 256, 256, 0, stream>>>(dst, deg);
    k_scan1<<<SCAN_NB, SCAN_B, 0, stream>>>(deg, blocksum);
    k_scan2<<<1, SCAN_B, 0, stream>>>(blocksum, blockoff, offs);
    k_scan3<<<SCAN_NB, SCAN_B, 0, stream>>>(deg, blockoff, offs, pos, inv_deg);
    k_scatter<<<(N_EDGES + 255) / 256, 256, 0, stream>>>(src, dst, pos, edge_src);

    // features -> bf16 (once); W fragment packing
    const int n2 = N_NODES * 128 / 2;
    k_f2bf<<<(n2 + 255) / 256, 256, 0, stream>>>((const float2*)features, (unsigned int*)fbf, n2);
    k_wprep<<<16, 256, 0, stream>>>(Ws0, Wn0, 128, frag0);
    k_wprep<<<16, 256, 0, stream>>>(Ws1, Wn1, 128, frag1);
    k_wprep<<<8, 256, 0, stream>>>(Ws2, Wn2, 64, frag2);

    const int aggGrid = (N_NODES * 64) / 256;  // 12500
    const int gemmGrid = (N_NODES + 63) / 64;  // 782

    // Layer 1
    k_agg<<<aggGrid, 256, 0, stream>>>(fbf, offs, edge_src, inv_deg, msg);
    k_gemm<8, false><<<gemmGrid, 256, 0, stream>>>(fbf, msg, frag0, b0, h1);
    // Layer 2
    k_agg<<<aggGrid, 256, 0, stream>>>(h1, offs, edge_src, inv_deg, msg);
    k_gemm<8, false><<<gemmGrid, 256, 0, stream>>>(h1, msg, frag1, b1, h2);
    // Layer 3
    k_agg<<<aggGrid, 256, 0, stream>>>(h2, offs, edge_src, inv_deg, msg);
    k_gemm<4, true><<<gemmGrid, 256, 0, stream>>>(h2, msg, frag2, b2, out);
}

// Round 8
// 325.957 us; speedup vs baseline: 1.8350x; 1.0041x over previous
//
#include <hip/hip_runtime.h>
#include <hip/hip_bf16.h>

#define N_NODES 50000
#define N_EDGES 800000
#define SCAN_B 256
#define SCAN_NB ((N_NODES + SCAN_B - 1) / SCAN_B)  // 196

typedef __attribute__((ext_vector_type(8))) short bf16x8;
typedef __attribute__((ext_vector_type(4))) float f32x4;

__device__ __forceinline__ float bf2f(unsigned short u) {
    unsigned int x = ((unsigned int)u) << 16;
    return __uint_as_float(x);
}
__device__ __forceinline__ unsigned short f2bf(float f) {
    unsigned int x = __float_as_uint(f);
    unsigned int lsb = (x >> 16) & 1u;
    x += 0x7fffu + lsb;
    return (unsigned short)(x >> 16);
}

// ---------------- CSR build (R6-proven path; R7's bucketed build produced
// persistent cross-call corruption — first call right, later calls stably
// wrong by ~0.31 — root cause unidentified, so it stays reverted) ----------------

__global__ void k_zero(int* p, int n) {
    int i = blockIdx.x * blockDim.x + threadIdx.x;
    if (i < n) p[i] = 0;
}

__global__ void k_deg(const int* __restrict__ dst, int* __restrict__ deg) {
    int e = blockIdx.x * blockDim.x + threadIdx.x;
    if (e < N_EDGES) atomicAdd(&deg[dst[e]], 1);
}

// hierarchical scan, stage 1: per-block sum (coalesced, whole GPU)
__global__ __launch_bounds__(SCAN_B) void k_scan1(const int* __restrict__ deg,
                                                  int* __restrict__ blocksum) {
    int i = blockIdx.x * SCAN_B + threadIdx.x;
    int v = (i < N_NODES) ? deg[i] : 0;
    #pragma unroll
    for (int d = 1; d < 64; d <<= 1) v += __shfl_xor(v, d);
    __shared__ int ws[SCAN_B / 64];
    int wv = threadIdx.x >> 6, lane = threadIdx.x & 63;
    if (lane == 0) ws[wv] = v;
    __syncthreads();
    if (threadIdx.x == 0) blocksum[blockIdx.x] = ws[0] + ws[1] + ws[2] + ws[3];
}

// stage 2: one small block scans the 196 block sums (8 barrier rounds)
__global__ __launch_bounds__(SCAN_B) void k_scan2(const int* __restrict__ blocksum,
                                                  int* __restrict__ blockoff,
                                                  int* __restrict__ offsets) {
    __shared__ int buf[SCAN_B];
    int tid = threadIdx.x;
    int v = (tid < SCAN_NB) ? blocksum[tid] : 0;
    buf[tid] = v;
    __syncthreads();
    for (int off = 1; off < SCAN_B; off <<= 1) {
        int t = (tid >= off) ? buf[tid - off] : 0;
        __syncthreads();
        buf[tid] += t;
        __syncthreads();
    }
    if (tid < SCAN_NB) blockoff[tid] = buf[tid] - v;  // exclusive
    if (tid == 0) offsets[N_NODES] = N_EDGES;         // total degree == E
}

// stage 3: per-block local scan (+ blockoff) -> offsets/pos/inv_deg
__global__ __launch_bounds__(SCAN_B) void k_scan3(const int* __restrict__ deg,
                                                  const int* __restrict__ blockoff,
                                                  int* __restrict__ offsets,
                                                  int* __restrict__ pos,
                                                  float* __restrict__ inv_deg) {
    int tid = threadIdx.x;
    int i = blockIdx.x * SCAN_B + tid;
    int v = (i < N_NODES) ? deg[i] : 0;
    int lane = tid & 63, wv = tid >> 6;
    int s = v;
    #pragma unroll
    for (int d = 1; d < 64; d <<= 1) {
        int t = __shfl_up(s, d);
        if (lane >= d) s += t;
    }
    __shared__ int wsum[SCAN_B / 64];
    if (lane == 63) wsum[wv] = s;
    __syncthreads();
    int add = 0;
    #pragma unroll
    for (int w = 0; w < SCAN_B / 64; ++w)
        if (w < wv) add += wsum[w];
    int excl = blockoff[blockIdx.x] + s + add - v;
    if (i < N_NODES) {
        offsets[i] = excl;
        pos[i] = excl;
        inv_deg[i] = 1.0f / (float)max(v, 1);
    }
}

__global__ void k_scatter(const int* __restrict__ src, const int* __restrict__ dst,
                          int* __restrict__ pos, int* __restrict__ edge_src) {
    int e = blockIdx.x * blockDim.x + threadIdx.x;
    if (e < N_EDGES) {
        int p = atomicAdd(&pos[dst[e]], 1);
        edge_src[p] = src[e];
    }
}

// ---------------- fp32 -> bf16 bulk convert (features, done once) ----------------
__global__ void k_f2bf(const float2* __restrict__ in, unsigned int* __restrict__ outp, int n2) {
    int i = blockIdx.x * blockDim.x + threadIdx.x;
    if (i < n2) {
        float2 v = in[i];
        outp[i] = ((unsigned int)f2bf(v.y) << 16) | (unsigned int)f2bf(v.x);
    }
}

// ---------------- mean aggregation (one wave per node, half-wave edge pairs) ----------------
// h: [N,128] bf16. half=lane>>5 picks edge parity, sub=lane&31 owns cols [4*sub..4*sub+3]
// via one dwordx2. Main loop: 16 edges/iter, 8 independent 8B gathers in flight per lane
// (~4KB/wave MLP). Cross-half combine via shfl_xor(32). fp32 accumulation.
__global__ void k_agg(const __hip_bfloat16* __restrict__ hv, const int* __restrict__ offsets,
                      const int* __restrict__ edge_src, const float* __restrict__ inv_deg,
                      __hip_bfloat16* __restrict__ msg) {
    int gid = blockIdx.x * blockDim.x + threadIdx.x;
    int node = gid >> 6;
    int lane = gid & 63;
    if (node >= N_NODES) return;
    int half = lane >> 5;
    int sub = lane & 31;
    int beg = offsets[node], end = offsets[node + 1];
    const uint2* hp = (const uint2*)hv;  // 32 uint2 per row

    float acc[4][4];
    #pragma unroll
    for (int g = 0; g < 4; ++g)
        #pragma unroll
        for (int c = 0; c < 4; ++c) acc[g][c] = 0.f;

    int i = beg;
    for (; i + 16 <= end; i += 16) {
        int s0 = edge_src[i + half];
        int s1 = edge_src[i + 2 + half];
        int s2 = edge_src[i + 4 + half];
        int s3 = edge_src[i + 6 + half];
        int s4 = edge_src[i + 8 + half];
        int s5 = edge_src[i + 10 + half];
        int s6 = edge_src[i + 12 + half];
        int s7 = edge_src[i + 14 + half];
        uint2 u0 = hp[(size_t)s0 * 32 + sub];
        uint2 u1 = hp[(size_t)s1 * 32 + sub];
        uint2 u2 = hp[(size_t)s2 * 32 + sub];
        uint2 u3 = hp[(size_t)s3 * 32 + sub];
        uint2 u4 = hp[(size_t)s4 * 32 + sub];
        uint2 u5 = hp[(size_t)s5 * 32 + sub];
        uint2 u6 = hp[(size_t)s6 * 32 + sub];
        uint2 u7 = hp[(size_t)s7 * 32 + sub];
        acc[0][0] += bf2f((unsigned short)(u0.x & 0xffffu)); acc[0][1] += bf2f((unsigned short)(u0.x >> 16));
        acc[0][2] += bf2f((unsigned short)(u0.y & 0xffffu)); acc[0][3] += bf2f((unsigned short)(u0.y >> 16));
        acc[1][0] += bf2f((unsigned short)(u1.x & 0xffffu)); acc[1][1] += bf2f((unsigned short)(u1.x >> 16));
        acc[1][2] += bf2f((unsigned short)(u1.y & 0xffffu)); acc[1][3] += bf2f((unsigned short)(u1.y >> 16));
        acc[2][0] += bf2f((unsigned short)(u2.x & 0xffffu)); acc[2][1] += bf2f((unsigned short)(u2.x >> 16));
        acc[2][2] += bf2f((unsigned short)(u2.y & 0xffffu)); acc[2][3] += bf2f((unsigned short)(u2.y >> 16));
        acc[3][0] += bf2f((unsigned short)(u3.x & 0xffffu)); acc[3][1] += bf2f((unsigned short)(u3.x >> 16));
        acc[3][2] += bf2f((unsigned short)(u3.y & 0xffffu)); acc[3][3] += bf2f((unsigned short)(u3.y >> 16));
        acc[0][0] += bf2f((unsigned short)(u4.x & 0xffffu)); acc[0][1] += bf2f((unsigned short)(u4.x >> 16));
        acc[0][2] += bf2f((unsigned short)(u4.y & 0xffffu)); acc[0][3] += bf2f((unsigned short)(u4.y >> 16));
        acc[1][0] += bf2f((unsigned short)(u5.x & 0xffffu)); acc[1][1] += bf2f((unsigned short)(u5.x >> 16));
        acc[1][2] += bf2f((unsigned short)(u5.y & 0xffffu)); acc[1][3] += bf2f((unsigned short)(u5.y >> 16));
        acc[2][0] += bf2f((unsigned short)(u6.x & 0xffffu)); acc[2][1] += bf2f((unsigned short)(u6.x >> 16));
        acc[2][2] += bf2f((unsigned short)(u6.y & 0xffffu)); acc[2][3] += bf2f((unsigned short)(u6.y >> 16));
        acc[3][0] += bf2f((unsigned short)(u7.x & 0xffffu)); acc[3][1] += bf2f((unsigned short)(u7.x >> 16));
        acc[3][2] += bf2f((unsigned short)(u7.y & 0xffffu)); acc[3][3] += bf2f((unsigned short)(u7.y >> 16));
    }
    for (; i + 8 <= end; i += 8) {
        int s0 = edge_src[i + half];
        int s1 = edge_src[i + 2 + half];
        int s2 = edge_src[i + 4 + half];
        int s3 = edge_src[i + 6 + half];
        uint2 u0 = hp[(size_t)s0 * 32 + sub];
        uint2 u1 = hp[(size_t)s1 * 32 + sub];
        uint2 u2 = hp[(size_t)s2 * 32 + sub];
        uint2 u3 = hp[(size_t)s3 * 32 + sub];
        acc[0][0] += bf2f((unsigned short)(u0.x & 0xffffu)); acc[0][1] += bf2f((unsigned short)(u0.x >> 16));
        acc[0][2] += bf2f((unsigned short)(u0.y & 0xffffu)); acc[0][3] += bf2f((unsigned short)(u0.y >> 16));
        acc[1][0] += bf2f((unsigned short)(u1.x & 0xffffu)); acc[1][1] += bf2f((unsigned short)(u1.x >> 16));
        acc[1][2] += bf2f((unsigned short)(u1.y & 0xffffu)); acc[1][3] += bf2f((unsigned short)(u1.y >> 16));
        acc[2][0] += bf2f((unsigned short)(u2.x & 0xffffu)); acc[2][1] += bf2f((unsigned short)(u2.x >> 16));
        acc[2][2] += bf2f((unsigned short)(u2.y & 0xffffu)); acc[2][3] += bf2f((unsigned short)(u2.y >> 16));
        acc[3][0] += bf2f((unsigned short)(u3.x & 0xffffu)); acc[3][1] += bf2f((unsigned short)(u3.x >> 16));
        acc[3][2] += bf2f((unsigned short)(u3.y & 0xffffu)); acc[3][3] += bf2f((unsigned short)(u3.y >> 16));
    }
    for (; i + 4 <= end; i += 4) {
        int s0 = edge_src[i + half];
        int s1 = edge_src[i + 2 + half];
        uint2 u0 = hp[(size_t)s0 * 32 + sub];
        uint2 u1 = hp[(size_t)s1 * 32 + sub];
        acc[0][0] += bf2f((unsigned short)(u0.x & 0xffffu)); acc[0][1] += bf2f((unsigned short)(u0.x >> 16));
        acc[0][2] += bf2f((unsigned short)(u0.y & 0xffffu)); acc[0][3] += bf2f((unsigned short)(u0.y >> 16));
        acc[1][0] += bf2f((unsigned short)(u1.x & 0xffffu)); acc[1][1] += bf2f((unsigned short)(u1.x >> 16));
        acc[1][2] += bf2f((unsigned short)(u1.y & 0xffffu)); acc[1][3] += bf2f((unsigned short)(u1.y >> 16));
    }
    for (; i + 2 <= end; i += 2) {
        int s0 = edge_src[i + half];
        uint2 u0 = hp[(size_t)s0 * 32 + sub];
        acc[0][0] += bf2f((unsigned short)(u0.x & 0xffffu)); acc[0][1] += bf2f((unsigned short)(u0.x >> 16));
        acc[0][2] += bf2f((unsigned short)(u0.y & 0xffffu)); acc[0][3] += bf2f((unsigned short)(u0.y >> 16));
    }
    if (i < end && half == 0) {  // odd leftover: half 0 only
        int s0 = edge_src[i];
        uint2 u0 = hp[(size_t)s0 * 32 + sub];
        acc[0][0] += bf2f((unsigned short)(u0.x & 0xffffu)); acc[0][1] += bf2f((unsigned short)(u0.x >> 16));
        acc[0][2] += bf2f((unsigned short)(u0.y & 0xffffu)); acc[0][3] += bf2f((unsigned short)(u0.y >> 16));
    }

    float r0 = acc[0][0] + acc[1][0] + acc[2][0] + acc[3][0];
    float r1 = acc[0][1] + acc[1][1] + acc[2][1] + acc[3][1];
    float r2 = acc[0][2] + acc[1][2] + acc[2][2] + acc[3][2];
    float r3 = acc[0][3] + acc[1][3] + acc[2][3] + acc[3][3];
    r0 += __shfl_xor(r0, 32);
    r1 += __shfl_xor(r1, 32);
    r2 += __shfl_xor(r2, 32);
    r3 += __shfl_xor(r3, 32);
    if (half == 0) {
        float w = inv_deg[node];
        uint2 o;
        o.x = ((unsigned int)f2bf(r1 * w) << 16) | (unsigned int)f2bf(r0 * w);
        o.y = ((unsigned int)f2bf(r3 * w) << 16) | (unsigned int)f2bf(r2 * w);
        ((uint2*)msg)[(size_t)node * 32 + sub] = o;
    }
}

// ---------------- W fragment packing (fp32 weights -> bf16 B-fragments) ----------------
// Bcat[k][n], k in [0,256): k<128 -> Wself[k][n], else Wneigh[k-128][n]. W row-major [128][Dout].
// frag: lane of (ct,kt) holds B[kt*32 + (lane>>4)*8 + j][ct*16 + (lane&15)], j=0..7.
__global__ void k_wprep(const float* __restrict__ Wself, const float* __restrict__ Wneigh,
                        int Dout, __hip_bfloat16* __restrict__ frag) {
    int t = blockIdx.x * blockDim.x + threadIdx.x;
    int nCt = Dout >> 4;
    int total = nCt * 8 * 64;
    if (t >= total) return;
    int lane = t & 63;
    int kt = (t >> 6) & 7;
    int ct = t >> 9;
    int q = lane >> 4;
    int n = ct * 16 + (lane & 15);
    unsigned short* dstp = (unsigned short*)frag + ((size_t)((ct * 8 + kt) * 64 + lane)) * 8;
    #pragma unroll
    for (int j = 0; j < 8; ++j) {
        int k = kt * 32 + q * 8 + j;
        float v = (k < 128) ? Wself[k * Dout + n] : Wneigh[(k - 128) * Dout + n];
        dstp[j] = f2bf(v);
    }
}

// ---------------- fused GEMM + bias (+ relu + l2norm) ----------------
// out[n][:] = epilogue( Aself[n]@Wself + Aneigh[n]@Wneigh + b ), K=256 fused via MFMA.
// Block = 256 threads = 4 waves; wave handles 16 rows x Dout cols.
// LAST: no relu/l2norm, output fp32; else output bf16.
template <int NCT, bool LAST>
__global__ __launch_bounds__(256) void k_gemm(const __hip_bfloat16* __restrict__ Aself,
                                              const __hip_bfloat16* __restrict__ Aneigh,
                                              const __hip_bfloat16* __restrict__ frag,
                                              const float* __restrict__ bias,
                                              void* __restrict__ out_) {
    constexpr int Dout = NCT * 16;
    int tid = threadIdx.x;
    int wv = tid >> 6, lane = tid & 63;
    int n0 = blockIdx.x * 64 + wv * 16;
    if (n0 >= N_NODES) return;  // wave-uniform early exit, no LDS used
    int q = lane >> 4, l15 = lane & 15;
    int rowA = n0 + l15;
    if (rowA > N_NODES - 1) rowA = N_NODES - 1;  // clamp loads; stores guarded below

    f32x4 acc[NCT];
    #pragma unroll
    for (int c = 0; c < NCT; ++c) acc[c] = (f32x4){0.f, 0.f, 0.f, 0.f};

    const bf16x8* fragv = (const bf16x8*)frag;
    #pragma unroll
    for (int kt = 0; kt < 8; ++kt) {
        int kb = (kt & 3) * 32 + q * 8;
        const __hip_bfloat16* Ab = (kt < 4) ? Aself : Aneigh;
        bf16x8 a = *(const bf16x8*)(Ab + (size_t)rowA * 128 + kb);
        #pragma unroll
        for (int ct = 0; ct < NCT; ++ct) {
            bf16x8 b = fragv[(ct * 8 + kt) * 64 + lane];
            acc[ct] = __builtin_amdgcn_mfma_f32_16x16x32_bf16(a, b, acc[ct], 0, 0, 0);
        }
    }

    float ss[4] = {0.f, 0.f, 0.f, 0.f};
    #pragma unroll
    for (int ct = 0; ct < NCT; ++ct) {
        float bc = bias[ct * 16 + l15];
        #pragma unroll
        for (int r = 0; r < 4; ++r) {
            float v = acc[ct][r] + bc;
            if (!LAST) v = fmaxf(v, 0.0f);
            acc[ct][r] = v;
            ss[r] += v * v;
        }
    }

    float scale[4];
    #pragma unroll
    for (int r = 0; r < 4; ++r) {
        if (!LAST) {
            float s = ss[r];
            s += __shfl_xor(s, 1);
            s += __shfl_xor(s, 2);
            s += __shfl_xor(s, 4);
            s += __shfl_xor(s, 8);
            scale[r] = 1.0f / fmaxf(sqrtf(s), 1e-12f);
        } else {
            scale[r] = 1.0f;
        }
    }

    #pragma unroll
    for (int ct = 0; ct < NCT; ++ct) {
        #pragma unroll
        for (int r = 0; r < 4; ++r) {
            int row = n0 + q * 4 + r;
            if (row < N_NODES) {
                float v = acc[ct][r] * scale[r];
                if (LAST)
                    ((float*)out_)[(size_t)row * Dout + ct * 16 + l15] = v;
                else
                    ((unsigned short*)out_)[(size_t)row * Dout + ct * 16 + l15] = f2bf(v);
            }
        }
    }
}

// ---------------- host launch ----------------

extern "C" void kernel_launch(void* const* d_in, const int* in_sizes, int n_in,
                              void* d_out, int out_size, void* d_ws, size_t ws_size,
                              hipStream_t stream) {
    const float* features = (const float*)d_in[0];
    const int* src = (const int*)d_in[1];
    const int* dst = (const int*)d_in[2];
    const float* Ws0 = (const float*)d_in[3];
    const float* Wn0 = (const float*)d_in[4];
    const float* b0  = (const float*)d_in[5];
    const float* Ws1 = (const float*)d_in[6];
    const float* Wn1 = (const float*)d_in[7];
    const float* b1  = (const float*)d_in[8];
    const float* Ws2 = (const float*)d_in[9];
    const float* Wn2 = (const float*)d_in[10];
    const float* b2  = (const float*)d_in[11];
    float* out = (float*)d_out;

    char* ws = (char*)d_ws;
    size_t off = 0;
    auto alloc = [&](size_t bytes) -> void* {
        void* p = ws + off;
        off = (off + bytes + 255) & ~(size_t)255;
        return p;
    };
    int*   deg      = (int*)alloc((size_t)N_NODES * 4);
    int*   offs     = (int*)alloc((size_t)(N_NODES + 1) * 4);
    int*   pos      = (int*)alloc((size_t)N_NODES * 4);
    int*   edge_src = (int*)alloc((size_t)N_EDGES * 4);
    float* inv_deg  = (float*)alloc((size_t)N_NODES * 4);
    int*   blocksum = (int*)alloc((size_t)SCAN_NB * 4);
    int*   blockoff = (int*)alloc((size_t)SCAN_NB * 4);
    __hip_bfloat16* fbf = (__hip_bfloat16*)alloc((size_t)N_NODES * 128 * 2);
    __hip_bfloat16* msg = (__hip_bfloat16*)alloc((size_t)N_NODES * 128 * 2);
    __hip_bfloat16* h1  = (__hip_bfloat16*)alloc((size_t)N_NODES * 128 * 2);
    __hip_bfloat16* h2  = (__hip_bfloat16*)alloc((size_t)N_NODES * 128 * 2);
    __hip_bfloat16* frag0 = (__hip_bfloat16*)alloc((size_t)8 * 8 * 64 * 8 * 2);
    __hip_bfloat16* frag1 = (__hip_bfloat16*)alloc((size_t)8 * 8 * 64 * 8 * 2);
    __hip_bfloat16* frag2 = (__hip_bfloat16*)alloc((size_t)4 * 8 * 64 * 8 * 2);

    // CSR build (parallel hierarchical scan; R6-proven)
    k_zero<<<(N_NODES + 255) / 256, 256, 0, stream>>>(deg, N_NODES);
    k_deg<<<(N_EDGES + 255) / 256, 256, 0, stream>>>(dst, deg);
    k_scan1<<<SCAN_NB, SCAN_B, 0, stream>>>(deg, blocksum);
    k_scan2<<<1, SCAN_B, 0, stream>>>(blocksum, blockoff, offs);
    k_scan3<<<SCAN_NB, SCAN_B, 0, stream>>>(deg, blockoff, offs, pos, inv_deg);
    k_scatter<<<(N_EDGES + 255) / 256, 256, 0, stream>>>(src, dst, pos, edge_src);

    // features -> bf16 (once); W fragment packing
    const int n2 = N_NODES * 128 / 2;
    k_f2bf<<<(n2 + 255) / 256, 256, 0, stream>>>((const float2*)features, (unsigned int*)fbf, n2);
    k_wprep<<<16, 256, 0, stream>>>(Ws0, Wn0, 128, frag0);
    k_wprep<<<16, 256, 0, stream>>>(Ws1, Wn1, 128, frag1);
    k_wprep<<<8, 256, 0, stream>>>(Ws2, Wn2, 64, frag2);

    const int aggGrid = (N_NODES * 64) / 256;  // 12500
    const int gemmGrid = (N_NODES + 63) / 64;  // 782

    // Layer 1
    k_agg<<<aggGrid, 256, 0, stream>>>(fbf, offs, edge_src, inv_deg, msg);
    k_gemm<8, false><<<gemmGrid, 256, 0, stream>>>(fbf, msg, frag0, b0, h1);
    // Layer 2
    k_agg<<<aggGrid, 256, 0, stream>>>(h1, offs, edge_src, inv_deg, msg);
    k_gemm<8, false><<<gemmGrid, 256, 0, stream>>>(h1, msg, frag1, b1, h2);
    // Layer 3
    k_agg<<<aggGrid, 256, 0, stream>>>(h2, offs, edge_src, inv_deg, msg);
    k_gemm<4, true><<<gemmGrid, 256, 0, stream>>>(h2, msg, frag2, b2, out);
}

// Round 9
// 323.368 us; speedup vs baseline: 1.8497x; 1.0080x over previous
//
#include <hip/hip_runtime.h>
#include <hip/hip_bf16.h>

#define N_NODES 50000
#define N_EDGES 800000
#define SCAN_B 256
#define SCAN_NB ((N_NODES + SCAN_B - 1) / SCAN_B)  // 196
#define CPAD 16  // counters padded to one per 64B line: 16x fewer cross-XCD line migrations

typedef __attribute__((ext_vector_type(8))) short bf16x8;
typedef __attribute__((ext_vector_type(4))) float f32x4;

__device__ __forceinline__ float bf2f(unsigned short u) {
    unsigned int x = ((unsigned int)u) << 16;
    return __uint_as_float(x);
}
__device__ __forceinline__ unsigned short f2bf(float f) {
    unsigned int x = __float_as_uint(f);
    unsigned int lsb = (x >> 16) & 1u;
    x += 0x7fffu + lsb;
    return (unsigned short)(x >> 16);
}

// ---------------- CSR build (R6-proven structure; counters line-padded) ----------------

__global__ void k_zero(int* p, int n) {
    int i = blockIdx.x * blockDim.x + threadIdx.x;
    if (i < n) p[i] = 0;
}

__global__ void k_deg(const int* __restrict__ dst, int* __restrict__ deg) {
    int e = blockIdx.x * blockDim.x + threadIdx.x;
    if (e < N_EDGES) atomicAdd(&deg[dst[e] * CPAD], 1);
}

// hierarchical scan, stage 1: per-block sum (line-strided deg reads)
__global__ __launch_bounds__(SCAN_B) void k_scan1(const int* __restrict__ deg,
                                                  int* __restrict__ blocksum) {
    int i = blockIdx.x * SCAN_B + threadIdx.x;
    int v = (i < N_NODES) ? deg[i * CPAD] : 0;
    #pragma unroll
    for (int d = 1; d < 64; d <<= 1) v += __shfl_xor(v, d);
    __shared__ int ws[SCAN_B / 64];
    int wv = threadIdx.x >> 6, lane = threadIdx.x & 63;
    if (lane == 0) ws[wv] = v;
    __syncthreads();
    if (threadIdx.x == 0) blocksum[blockIdx.x] = ws[0] + ws[1] + ws[2] + ws[3];
}

// stage 2: one small block scans the 196 block sums
__global__ __launch_bounds__(SCAN_B) void k_scan2(const int* __restrict__ blocksum,
                                                  int* __restrict__ blockoff,
                                                  int* __restrict__ offsets) {
    __shared__ int buf[SCAN_B];
    int tid = threadIdx.x;
    int v = (tid < SCAN_NB) ? blocksum[tid] : 0;
    buf[tid] = v;
    __syncthreads();
    for (int off = 1; off < SCAN_B; off <<= 1) {
        int t = (tid >= off) ? buf[tid - off] : 0;
        __syncthreads();
        buf[tid] += t;
        __syncthreads();
    }
    if (tid < SCAN_NB) blockoff[tid] = buf[tid] - v;  // exclusive
    if (tid == 0) offsets[N_NODES] = N_EDGES;         // total degree == E
}

// stage 3: per-block local scan (+ blockoff) -> offsets/pos/inv_deg
__global__ __launch_bounds__(SCAN_B) void k_scan3(const int* __restrict__ deg,
                                                  const int* __restrict__ blockoff,
                                                  int* __restrict__ offsets,
                                                  int* __restrict__ pos,
                                                  float* __restrict__ inv_deg) {
    int tid = threadIdx.x;
    int i = blockIdx.x * SCAN_B + tid;
    int v = (i < N_NODES) ? deg[i * CPAD] : 0;
    int lane = tid & 63, wv = tid >> 6;
    int s = v;
    #pragma unroll
    for (int d = 1; d < 64; d <<= 1) {
        int t = __shfl_up(s, d);
        if (lane >= d) s += t;
    }
    __shared__ int wsum[SCAN_B / 64];
    if (lane == 63) wsum[wv] = s;
    __syncthreads();
    int add = 0;
    #pragma unroll
    for (int w = 0; w < SCAN_B / 64; ++w)
        if (w < wv) add += wsum[w];
    int excl = blockoff[blockIdx.x] + s + add - v;
    if (i < N_NODES) {
        offsets[i] = excl;
        pos[i * CPAD] = excl;
        inv_deg[i] = 1.0f / (float)max(v, 1);
    }
}

__global__ void k_scatter(const int* __restrict__ src, const int* __restrict__ dst,
                          int* __restrict__ pos, int* __restrict__ edge_src) {
    int e = blockIdx.x * blockDim.x + threadIdx.x;
    if (e < N_EDGES) {
        int p = atomicAdd(&pos[dst[e] * CPAD], 1);
        edge_src[p] = src[e];
    }
}

// ---------------- fp32 -> bf16 bulk convert (features, done once) ----------------
__global__ void k_f2bf(const float2* __restrict__ in, unsigned int* __restrict__ outp, int n2) {
    int i = blockIdx.x * blockDim.x + threadIdx.x;
    if (i < n2) {
        float2 v = in[i];
        outp[i] = ((unsigned int)f2bf(v.y) << 16) | (unsigned int)f2bf(v.x);
    }
}

// ---------------- mean aggregation (one wave per node, half-wave edge pairs) ----------------
// h: [N,128] bf16. half=lane>>5 picks edge parity, sub=lane&31 owns cols [4*sub..4*sub+3]
// via one dwordx2. Main loop: 16 edges/iter, 8 independent 8B gathers in flight per lane.
// At the scattered-gather pipe ceiling (~2.3 TB/s HBM-side) — deeper MLP is neutral (R8).
__global__ void k_agg(const __hip_bfloat16* __restrict__ hv, const int* __restrict__ offsets,
                      const int* __restrict__ edge_src, const float* __restrict__ inv_deg,
                      __hip_bfloat16* __restrict__ msg) {
    int gid = blockIdx.x * blockDim.x + threadIdx.x;
    int node = gid >> 6;
    int lane = gid & 63;
    if (node >= N_NODES) return;
    int half = lane >> 5;
    int sub = lane & 31;
    int beg = offsets[node], end = offsets[node + 1];
    const uint2* hp = (const uint2*)hv;  // 32 uint2 per row

    float acc[4][4];
    #pragma unroll
    for (int g = 0; g < 4; ++g)
        #pragma unroll
        for (int c = 0; c < 4; ++c) acc[g][c] = 0.f;

    int i = beg;
    for (; i + 16 <= end; i += 16) {
        int s0 = edge_src[i + half];
        int s1 = edge_src[i + 2 + half];
        int s2 = edge_src[i + 4 + half];
        int s3 = edge_src[i + 6 + half];
        int s4 = edge_src[i + 8 + half];
        int s5 = edge_src[i + 10 + half];
        int s6 = edge_src[i + 12 + half];
        int s7 = edge_src[i + 14 + half];
        uint2 u0 = hp[(size_t)s0 * 32 + sub];
        uint2 u1 = hp[(size_t)s1 * 32 + sub];
        uint2 u2 = hp[(size_t)s2 * 32 + sub];
        uint2 u3 = hp[(size_t)s3 * 32 + sub];
        uint2 u4 = hp[(size_t)s4 * 32 + sub];
        uint2 u5 = hp[(size_t)s5 * 32 + sub];
        uint2 u6 = hp[(size_t)s6 * 32 + sub];
        uint2 u7 = hp[(size_t)s7 * 32 + sub];
        acc[0][0] += bf2f((unsigned short)(u0.x & 0xffffu)); acc[0][1] += bf2f((unsigned short)(u0.x >> 16));
        acc[0][2] += bf2f((unsigned short)(u0.y & 0xffffu)); acc[0][3] += bf2f((unsigned short)(u0.y >> 16));
        acc[1][0] += bf2f((unsigned short)(u1.x & 0xffffu)); acc[1][1] += bf2f((unsigned short)(u1.x >> 16));
        acc[1][2] += bf2f((unsigned short)(u1.y & 0xffffu)); acc[1][3] += bf2f((unsigned short)(u1.y >> 16));
        acc[2][0] += bf2f((unsigned short)(u2.x & 0xffffu)); acc[2][1] += bf2f((unsigned short)(u2.x >> 16));
        acc[2][2] += bf2f((unsigned short)(u2.y & 0xffffu)); acc[2][3] += bf2f((unsigned short)(u2.y >> 16));
        acc[3][0] += bf2f((unsigned short)(u3.x & 0xffffu)); acc[3][1] += bf2f((unsigned short)(u3.x >> 16));
        acc[3][2] += bf2f((unsigned short)(u3.y & 0xffffu)); acc[3][3] += bf2f((unsigned short)(u3.y >> 16));
        acc[0][0] += bf2f((unsigned short)(u4.x & 0xffffu)); acc[0][1] += bf2f((unsigned short)(u4.x >> 16));
        acc[0][2] += bf2f((unsigned short)(u4.y & 0xffffu)); acc[0][3] += bf2f((unsigned short)(u4.y >> 16));
        acc[1][0] += bf2f((unsigned short)(u5.x & 0xffffu)); acc[1][1] += bf2f((unsigned short)(u5.x >> 16));
        acc[1][2] += bf2f((unsigned short)(u5.y & 0xffffu)); acc[1][3] += bf2f((unsigned short)(u5.y >> 16));
        acc[2][0] += bf2f((unsigned short)(u6.x & 0xffffu)); acc[2][1] += bf2f((unsigned short)(u6.x >> 16));
        acc[2][2] += bf2f((unsigned short)(u6.y & 0xffffu)); acc[2][3] += bf2f((unsigned short)(u6.y >> 16));
        acc[3][0] += bf2f((unsigned short)(u7.x & 0xffffu)); acc[3][1] += bf2f((unsigned short)(u7.x >> 16));
        acc[3][2] += bf2f((unsigned short)(u7.y & 0xffffu)); acc[3][3] += bf2f((unsigned short)(u7.y >> 16));
    }
    for (; i + 8 <= end; i += 8) {
        int s0 = edge_src[i + half];
        int s1 = edge_src[i + 2 + half];
        int s2 = edge_src[i + 4 + half];
        int s3 = edge_src[i + 6 + half];
        uint2 u0 = hp[(size_t)s0 * 32 + sub];
        uint2 u1 = hp[(size_t)s1 * 32 + sub];
        uint2 u2 = hp[(size_t)s2 * 32 + sub];
        uint2 u3 = hp[(size_t)s3 * 32 + sub];
        acc[0][0] += bf2f((unsigned short)(u0.x & 0xffffu)); acc[0][1] += bf2f((unsigned short)(u0.x >> 16));
        acc[0][2] += bf2f((unsigned short)(u0.y & 0xffffu)); acc[0][3] += bf2f((unsigned short)(u0.y >> 16));
        acc[1][0] += bf2f((unsigned short)(u1.x & 0xffffu)); acc[1][1] += bf2f((unsigned short)(u1.x >> 16));
        acc[1][2] += bf2f((unsigned short)(u1.y & 0xffffu)); acc[1][3] += bf2f((unsigned short)(u1.y >> 16));
        acc[2][0] += bf2f((unsigned short)(u2.x & 0xffffu)); acc[2][1] += bf2f((unsigned short)(u2.x >> 16));
        acc[2][2] += bf2f((unsigned short)(u2.y & 0xffffu)); acc[2][3] += bf2f((unsigned short)(u2.y >> 16));
        acc[3][0] += bf2f((unsigned short)(u3.x & 0xffffu)); acc[3][1] += bf2f((unsigned short)(u3.x >> 16));
        acc[3][2] += bf2f((unsigned short)(u3.y & 0xffffu)); acc[3][3] += bf2f((unsigned short)(u3.y >> 16));
    }
    for (; i + 4 <= end; i += 4) {
        int s0 = edge_src[i + half];
        int s1 = edge_src[i + 2 + half];
        uint2 u0 = hp[(size_t)s0 * 32 + sub];
        uint2 u1 = hp[(size_t)s1 * 32 + sub];
        acc[0][0] += bf2f((unsigned short)(u0.x & 0xffffu)); acc[0][1] += bf2f((unsigned short)(u0.x >> 16));
        acc[0][2] += bf2f((unsigned short)(u0.y & 0xffffu)); acc[0][3] += bf2f((unsigned short)(u0.y >> 16));
        acc[1][0] += bf2f((unsigned short)(u1.x & 0xffffu)); acc[1][1] += bf2f((unsigned short)(u1.x >> 16));
        acc[1][2] += bf2f((unsigned short)(u1.y & 0xffffu)); acc[1][3] += bf2f((unsigned short)(u1.y >> 16));
    }
    for (; i + 2 <= end; i += 2) {
        int s0 = edge_src[i + half];
        uint2 u0 = hp[(size_t)s0 * 32 + sub];
        acc[0][0] += bf2f((unsigned short)(u0.x & 0xffffu)); acc[0][1] += bf2f((unsigned short)(u0.x >> 16));
        acc[0][2] += bf2f((unsigned short)(u0.y & 0xffffu)); acc[0][3] += bf2f((unsigned short)(u0.y >> 16));
    }
    if (i < end && half == 0) {  // odd leftover: half 0 only
        int s0 = edge_src[i];
        uint2 u0 = hp[(size_t)s0 * 32 + sub];
        acc[0][0] += bf2f((unsigned short)(u0.x & 0xffffu)); acc[0][1] += bf2f((unsigned short)(u0.x >> 16));
        acc[0][2] += bf2f((unsigned short)(u0.y & 0xffffu)); acc[0][3] += bf2f((unsigned short)(u0.y >> 16));
    }

    float r0 = acc[0][0] + acc[1][0] + acc[2][0] + acc[3][0];
    float r1 = acc[0][1] + acc[1][1] + acc[2][1] + acc[3][1];
    float r2 = acc[0][2] + acc[1][2] + acc[2][2] + acc[3][2];
    float r3 = acc[0][3] + acc[1][3] + acc[2][3] + acc[3][3];
    r0 += __shfl_xor(r0, 32);
    r1 += __shfl_xor(r1, 32);
    r2 += __shfl_xor(r2, 32);
    r3 += __shfl_xor(r3, 32);
    if (half == 0) {
        float w = inv_deg[node];
        uint2 o;
        o.x = ((unsigned int)f2bf(r1 * w) << 16) | (unsigned int)f2bf(r0 * w);
        o.y = ((unsigned int)f2bf(r3 * w) << 16) | (unsigned int)f2bf(r2 * w);
        ((uint2*)msg)[(size_t)node * 32 + sub] = o;
    }
}

// ---------------- W fragment packing: all 3 layers in ONE launch ----------------
// blocks [0,16): layer0 (Dout=128), [16,32): layer1 (128), [32,40): layer2 (64).
// frag: lane of (ct,kt) holds B[kt*32 + (lane>>4)*8 + j][ct*16 + (lane&15)], j=0..7.
__global__ __launch_bounds__(256) void k_wprep3(
        const float* __restrict__ Ws0, const float* __restrict__ Wn0,
        const float* __restrict__ Ws1, const float* __restrict__ Wn1,
        const float* __restrict__ Ws2, const float* __restrict__ Wn2,
        __hip_bfloat16* __restrict__ frag0, __hip_bfloat16* __restrict__ frag1,
        __hip_bfloat16* __restrict__ frag2) {
    int b = blockIdx.x;
    const float* Wself;
    const float* Wneigh;
    __hip_bfloat16* frag;
    int Dout, lb;
    if (b < 16)      { Wself = Ws0; Wneigh = Wn0; frag = frag0; Dout = 128; lb = b; }
    else if (b < 32) { Wself = Ws1; Wneigh = Wn1; frag = frag1; Dout = 128; lb = b - 16; }
    else             { Wself = Ws2; Wneigh = Wn2; frag = frag2; Dout = 64;  lb = b - 32; }
    int t = lb * 256 + threadIdx.x;
    int nCt = Dout >> 4;
    int total = nCt * 8 * 64;
    if (t >= total) return;
    int lane = t & 63;
    int kt = (t >> 6) & 7;
    int ct = t >> 9;
    int q = lane >> 4;
    int n = ct * 16 + (lane & 15);
    unsigned short* dstp = (unsigned short*)frag + ((size_t)((ct * 8 + kt) * 64 + lane)) * 8;
    #pragma unroll
    for (int j = 0; j < 8; ++j) {
        int k = kt * 32 + q * 8 + j;
        float v = (k < 128) ? Wself[k * Dout + n] : Wneigh[(k - 128) * Dout + n];
        dstp[j] = f2bf(v);
    }
}

// ---------------- fused GEMM + bias (+ relu + l2norm) ----------------
template <int NCT, bool LAST>
__global__ __launch_bounds__(256) void k_gemm(const __hip_bfloat16* __restrict__ Aself,
                                              const __hip_bfloat16* __restrict__ Aneigh,
                                              const __hip_bfloat16* __restrict__ frag,
                                              const float* __restrict__ bias,
                                              void* __restrict__ out_) {
    constexpr int Dout = NCT * 16;
    int tid = threadIdx.x;
    int wv = tid >> 6, lane = tid & 63;
    int n0 = blockIdx.x * 64 + wv * 16;
    if (n0 >= N_NODES) return;  // wave-uniform early exit, no LDS used
    int q = lane >> 4, l15 = lane & 15;
    int rowA = n0 + l15;
    if (rowA > N_NODES - 1) rowA = N_NODES - 1;  // clamp loads; stores guarded below

    f32x4 acc[NCT];
    #pragma unroll
    for (int c = 0; c < NCT; ++c) acc[c] = (f32x4){0.f, 0.f, 0.f, 0.f};

    const bf16x8* fragv = (const bf16x8*)frag;
    #pragma unroll
    for (int kt = 0; kt < 8; ++kt) {
        int kb = (kt & 3) * 32 + q * 8;
        const __hip_bfloat16* Ab = (kt < 4) ? Aself : Aneigh;
        bf16x8 a = *(const bf16x8*)(Ab + (size_t)rowA * 128 + kb);
        #pragma unroll
        for (int ct = 0; ct < NCT; ++ct) {
            bf16x8 b = fragv[(ct * 8 + kt) * 64 + lane];
            acc[ct] = __builtin_amdgcn_mfma_f32_16x16x32_bf16(a, b, acc[ct], 0, 0, 0);
        }
    }

    float ss[4] = {0.f, 0.f, 0.f, 0.f};
    #pragma unroll
    for (int ct = 0; ct < NCT; ++ct) {
        float bc = bias[ct * 16 + l15];
        #pragma unroll
        for (int r = 0; r < 4; ++r) {
            float v = acc[ct][r] + bc;
            if (!LAST) v = fmaxf(v, 0.0f);
            acc[ct][r] = v;
            ss[r] += v * v;
        }
    }

    float scale[4];
    #pragma unroll
    for (int r = 0; r < 4; ++r) {
        if (!LAST) {
            float s = ss[r];
            s += __shfl_xor(s, 1);
            s += __shfl_xor(s, 2);
            s += __shfl_xor(s, 4);
            s += __shfl_xor(s, 8);
            scale[r] = 1.0f / fmaxf(sqrtf(s), 1e-12f);
        } else {
            scale[r] = 1.0f;
        }
    }

    #pragma unroll
    for (int ct = 0; ct < NCT; ++ct) {
        #pragma unroll
        for (int r = 0; r < 4; ++r) {
            int row = n0 + q * 4 + r;
            if (row < N_NODES) {
                float v = acc[ct][r] * scale[r];
                if (LAST)
                    ((float*)out_)[(size_t)row * Dout + ct * 16 + l15] = v;
                else
                    ((unsigned short*)out_)[(size_t)row * Dout + ct * 16 + l15] = f2bf(v);
            }
        }
    }
}

// ---------------- host launch ----------------

extern "C" void kernel_launch(void* const* d_in, const int* in_sizes, int n_in,
                              void* d_out, int out_size, void* d_ws, size_t ws_size,
                              hipStream_t stream) {
    const float* features = (const float*)d_in[0];
    const int* src = (const int*)d_in[1];
    const int* dst = (const int*)d_in[2];
    const float* Ws0 = (const float*)d_in[3];
    const float* Wn0 = (const float*)d_in[4];
    const float* b0  = (const float*)d_in[5];
    const float* Ws1 = (const float*)d_in[6];
    const float* Wn1 = (const float*)d_in[7];
    const float* b1  = (const float*)d_in[8];
    const float* Ws2 = (const float*)d_in[9];
    const float* Wn2 = (const float*)d_in[10];
    const float* b2  = (const float*)d_in[11];
    float* out = (float*)d_out;

    char* ws = (char*)d_ws;
    size_t off = 0;
    auto alloc = [&](size_t bytes) -> void* {
        void* p = ws + off;
        off = (off + bytes + 255) & ~(size_t)255;
        return p;
    };
    int*   deg      = (int*)alloc((size_t)N_NODES * CPAD * 4);  // line-padded counters
    int*   pos      = (int*)alloc((size_t)N_NODES * CPAD * 4);  // line-padded counters
    int*   offs     = (int*)alloc((size_t)(N_NODES + 1) * 4);
    int*   edge_src = (int*)alloc((size_t)N_EDGES * 4);
    float* inv_deg  = (float*)alloc((size_t)N_NODES * 4);
    int*   blocksum = (int*)alloc((size_t)SCAN_NB * 4);
    int*   blockoff = (int*)alloc((size_t)SCAN_NB * 4);
    __hip_bfloat16* fbf = (__hip_bfloat16*)alloc((size_t)N_NODES * 128 * 2);
    __hip_bfloat16* msg = (__hip_bfloat16*)alloc((size_t)N_NODES * 128 * 2);
    __hip_bfloat16* h1  = (__hip_bfloat16*)alloc((size_t)N_NODES * 128 * 2);
    __hip_bfloat16* h2  = (__hip_bfloat16*)alloc((size_t)N_NODES * 128 * 2);
    __hip_bfloat16* frag0 = (__hip_bfloat16*)alloc((size_t)8 * 8 * 64 * 8 * 2);
    __hip_bfloat16* frag1 = (__hip_bfloat16*)alloc((size_t)8 * 8 * 64 * 8 * 2);
    __hip_bfloat16* frag2 = (__hip_bfloat16*)alloc((size_t)4 * 8 * 64 * 8 * 2);

    // CSR build (parallel hierarchical scan; R6-proven structure, padded counters)
    k_zero<<<(N_NODES * CPAD + 255) / 256, 256, 0, stream>>>(deg, N_NODES * CPAD);
    k_deg<<<(N_EDGES + 255) / 256, 256, 0, stream>>>(dst, deg);
    k_scan1<<<SCAN_NB, SCAN_B, 0, stream>>>(deg, blocksum);
    k_scan2<<<1, SCAN_B, 0, stream>>>(blocksum, blockoff, offs);
    k_scan3<<<SCAN_NB, SCAN_B, 0, stream>>>(deg, blockoff, offs, pos, inv_deg);
    k_scatter<<<(N_EDGES + 255) / 256, 256, 0, stream>>>(src, dst, pos, edge_src);

    // features -> bf16 (once); W fragment packing (single launch for 3 layers)
    const int n2 = N_NODES * 128 / 2;
    k_f2bf<<<(n2 + 255) / 256, 256, 0, stream>>>((const float2*)features, (unsigned int*)fbf, n2);
    k_wprep3<<<40, 256, 0, stream>>>(Ws0, Wn0, Ws1, Wn1, Ws2, Wn2, frag0, frag1, frag2);

    const int aggGrid = (N_NODES * 64) / 256;  // 12500
    const int gemmGrid = (N_NODES + 63) / 64;  // 782

    // Layer 1
    k_agg<<<aggGrid, 256, 0, stream>>>(fbf, offs, edge_src, inv_deg, msg);
    k_gemm<8, false><<<gemmGrid, 256, 0, stream>>>(fbf, msg, frag0, b0, h1);
    // Layer 2
    k_agg<<<aggGrid, 256, 0, stream>>>(h1, offs, edge_src, inv_deg, msg);
    k_gemm<8, false><<<gemmGrid, 256, 0, stream>>>(h1, msg, frag1, b1, h2);
    // Layer 3
    k_agg<<<aggGrid, 256, 0, stream>>>(h2, offs, edge_src, inv_deg, msg);
    k_gemm<4, true><<<gemmGrid, 256, 0, stream>>>(h2, msg, frag2, b2, out);
}